// Round 11
// baseline (1398.427 us; speedup 1.0000x reference)
//
#include <hip/hip_runtime.h>

#define ND 64        // feature dim
#define NR 8         // num edge types
#define NSLICE 8     // dst slices (XCD count)
#define SLICE_NODES 6272   // 196*32, multiple of 32; 8*6272 >= 50000
#define TPS 196      // tiles per slice (32 nodes each)
#define NTILE_AL 1568
#define CAPA 216064  // per-slice bucket capacity (mean 200704, ~35 sigma)
#define CAPB 1536    // per-tile bucket capacity (mean 1024, 16 sigma; multiple of 64)
#define AGSTRIDE 65  // padded row stride (bank-conflict fix)

typedef __bf16 bf16x8 __attribute__((ext_vector_type(8)));
typedef float f32x4 __attribute__((ext_vector_type(4)));
typedef unsigned short us8 __attribute__((ext_vector_type(8)));

__device__ inline unsigned short bf16_rne(float f) {
    unsigned u = __float_as_uint(f);
    unsigned r = (u + 0x7FFFu + ((u >> 16) & 1u)) >> 16;
    return (unsigned short)r;
}
__device__ inline float bf16_to_f(unsigned short s) {
    return __uint_as_float(((unsigned)s) << 16);
}

// ---------------------------------------------------------------- zero ints
__global__ __launch_bounds__(256) void zeroi_kernel(int* __restrict__ p, int n) {
    int i = blockIdx.x * 256 + threadIdx.x;
    int stride = gridDim.x * 256;
    for (; i < n; i += stride) p[i] = 0;
}

// ---------------------------------------------------------------- A1: bucket edges into 8 dst-slices
__global__ __launch_bounds__(256) void bucket8_kernel(
    const int* __restrict__ src, const int* __restrict__ dst,
    const int* __restrict__ typ, int* __restrict__ bcur,
    uint2* __restrict__ bbufA, int nEdges)
{
    __shared__ uint2 outst[1024];
    __shared__ int lcnt[NSLICE];
    __shared__ int lbase[NSLICE];
    __shared__ int gbase[NSLICE];
    int tid = threadIdx.x;

    for (int base = blockIdx.x * 1024; base < nEdges; base += gridDim.x * 1024) {
        int bn = min(1024, nEdges - base);
        if (tid < NSLICE) lcnt[tid] = 0;
        __syncthreads();
        uint2 ent[4]; int eb[4], eo[4];
#pragma unroll
        for (int k = 0; k < 4; ++k) {
            int i = tid + k * 256;
            eb[k] = -1;
            if (i < bn) {
                int e = base + i;
                int d = dst[e];
                int s = d / SLICE_NODES;
                eb[k] = s;
                ent[k].x = (unsigned)src[e];
                ent[k].y = ((unsigned)s << 16) | ((unsigned)typ[e] << 13) |
                           (unsigned)(d - s * SLICE_NODES);
                eo[k] = atomicAdd(&lcnt[s], 1);
            }
        }
        __syncthreads();
        if (tid == 0) {
            int run = 0;
#pragma unroll
            for (int i = 0; i < NSLICE; ++i) { lbase[i] = run; run += lcnt[i]; }
        }
        if (tid < NSLICE && lcnt[tid] > 0) gbase[tid] = atomicAdd(&bcur[tid], lcnt[tid]);
        __syncthreads();
#pragma unroll
        for (int k = 0; k < 4; ++k)
            if (eb[k] >= 0) outst[lbase[eb[k]] + eo[k]] = ent[k];
        __syncthreads();
#pragma unroll
        for (int k = 0; k < 4; ++k) {
            int i = tid + k * 256;
            if (i < bn) {
                uint2 e = outst[i];
                int s = e.y >> 16;
                bbufA[(long)s * CAPA + gbase[s] + (i - lbase[s])] = e;
            }
        }
        __syncthreads();
    }
}

// ---------------------------------------------------------------- A2: per-slice re-bin into 196 node-tiles
__global__ __launch_bounds__(256) void subbucket_kernel(
    const uint2* __restrict__ bbufA, const int* __restrict__ bcur,
    int* __restrict__ tilecur, uint2* __restrict__ bbufB)
{
    __shared__ uint2 outst[2048];
    __shared__ int lcnt[TPS];
    __shared__ int lbase[TPS];
    __shared__ int gbase[TPS];
    __shared__ int scanbuf[256];
    int tid = threadIdx.x;
    int slice = blockIdx.x & 7;
    int chunk = blockIdx.x >> 3;
    int nchunk = gridDim.x >> 3;
    int n = bcur[slice];
    const uint2* in = bbufA + (long)slice * CAPA;
    int per = (n + nchunk - 1) / nchunk;
    int beg = chunk * per;
    int end = min(beg + per, n);

    for (int b0 = beg; b0 < end; b0 += 2048) {
        int bn = min(2048, end - b0);
        if (tid < TPS) lcnt[tid] = 0;
        __syncthreads();
        uint2 ent[8]; int eb[8], eo[8];
#pragma unroll
        for (int k = 0; k < 8; ++k) {
            int i = tid + k * 256;
            eb[k] = -1;
            if (i < bn) {
                ent[k] = in[b0 + i];
                int bin = (ent[k].y & 8191u) >> 5;
                eb[k] = bin;
                eo[k] = atomicAdd(&lcnt[bin], 1);
            }
        }
        __syncthreads();
        int v = (tid < TPS) ? lcnt[tid] : 0;
        scanbuf[tid] = v;
        __syncthreads();
        int xs = v;
        for (int off = 1; off < 256; off <<= 1) {
            int y = (tid >= off) ? scanbuf[tid - off] : 0;
            __syncthreads();
            xs += y;
            scanbuf[tid] = xs;
            __syncthreads();
        }
        if (tid < TPS) {
            lbase[tid] = xs - v;
            if (v > 0) gbase[tid] = atomicAdd(&tilecur[slice * TPS + tid], v);
        }
        __syncthreads();
#pragma unroll
        for (int k = 0; k < 8; ++k)
            if (eb[k] >= 0) outst[lbase[eb[k]] + eo[k]] = ent[k];
        __syncthreads();
#pragma unroll
        for (int k = 0; k < 8; ++k) {
            int i = tid + k * 256;
            if (i < bn) {
                uint2 e = outst[i];
                int bin = (e.y & 8191u) >> 5;
                bbufB[(long)(slice * TPS + bin) * CAPB + gbase[bin] + (i - lbase[bin])] = e;
            }
        }
        __syncthreads();
    }
}

// ---------------------------------------------------------------- weight convert+transpose (relation W)
__global__ __launch_bounds__(256) void convw_kernel(
    const float* __restrict__ W, unsigned short* __restrict__ wt)
{
    int idx = blockIdx.x * 256 + threadIdx.x;
    if (idx >= 64 * 512) return;
    int o = idx >> 9, k = idx & 511;
    wt[idx] = bf16_rne(W[(long)k * 64 + o]);
}

// ---------------------------------------------------------------- MLP weight convert+transpose
__global__ __launch_bounds__(256) void convm_kernel(
    const float* __restrict__ m, unsigned short* __restrict__ wmt)
{
    int idx = blockIdx.x * 256 + threadIdx.x;
    if (idx >= 64 * 64) return;
    int o = idx >> 6, k = idx & 63;
    wmt[idx] = bf16_rne(m[k * 64 + o]);
}

// ---------------------------------------------------------------- x -> bf16
__global__ __launch_bounds__(256) void convx_kernel(
    const float4* __restrict__ x, unsigned short* __restrict__ xb, int n8)
{
    int i = blockIdx.x * 256 + threadIdx.x;
    if (i >= n8) return;
    float4 v0 = x[i * 2], v1 = x[i * 2 + 1];
    us8 o;
    o[0] = bf16_rne(v0.x); o[1] = bf16_rne(v0.y);
    o[2] = bf16_rne(v0.z); o[3] = bf16_rne(v0.w);
    o[4] = bf16_rne(v1.x); o[5] = bf16_rne(v1.y);
    o[6] = bf16_rne(v1.z); o[7] = bf16_rne(v1.w);
    *(us8*)(xb + (long)i * 8) = o;
}

// ---------------------------------------------------------------- B: per-tile LDS aggregation (latency-tolerant rewrite)
// Per 32-node tile: stage edge list in LDS (kills the buf->xb dependent chain),
// 16-lane groups with a 4-deep load pipeline (16 row-loads in flight/wave),
// padded ag rows (stride 65) to spread LDS-atomic banks, sentinel-padded tail.
__global__ __launch_bounds__(256) void aggregate_kernel(
    const unsigned short* __restrict__ xb, const uint2* __restrict__ bbufB,
    const int* __restrict__ tilecur, unsigned short* __restrict__ agbf, int nNodes)
{
    __shared__ float agf[NR * 32 * AGSTRIDE + 64];   // padded tile + trash row
    __shared__ uint2 ebuf[CAPB];
    float* trash = agf + NR * 32 * AGSTRIDE;

    int tile = blockIdx.x;
    int tid = threadIdx.x;

    for (int i = tid; i < NR * 32 * AGSTRIDE + 64; i += 256) agf[i] = 0.f;

    int n = tilecur[tile];
    int n_pad = (n + 63) & ~63;
    const uint2* buf = bbufB + (long)tile * CAPB;
    for (int i = tid; i < n_pad; i += 256) {
        uint2 e;
        if (i < n) e = buf[i];
        else { e.x = 0u; e.y = 0xFFFFFFFFu; }   // sentinel -> trash row
        ebuf[i] = e;
    }
    __syncthreads();

    int grp = tid >> 4;      // 16 groups of 16 lanes
    int fl = tid & 15;       // lane's 4-feature slice

    for (int i = grp; i < n_pad; i += 64) {
        uint2 E0 = ebuf[i];
        uint2 E1 = ebuf[i + 16];
        uint2 E2 = ebuf[i + 32];
        uint2 E3 = ebuf[i + 48];
        // 4 independent row loads issued before any use
        ushort4 V0 = *(const ushort4*)(xb + (long)E0.x * ND + fl * 4);
        ushort4 V1 = *(const ushort4*)(xb + (long)E1.x * ND + fl * 4);
        ushort4 V2 = *(const ushort4*)(xb + (long)E2.x * ND + fl * 4);
        ushort4 V3 = *(const ushort4*)(xb + (long)E3.x * ND + fl * 4);
#define ACC1(E, V)                                                          \
        {                                                                   \
            float* dstp = (E.y == 0xFFFFFFFFu) ? (trash + fl * 4)           \
                : (agf + ((((E.y >> 13) & 7) << 5) | (E.y & 31)) * AGSTRIDE \
                   + fl * 4);                                               \
            atomicAdd(dstp + 0, bf16_to_f(V.x));                            \
            atomicAdd(dstp + 1, bf16_to_f(V.y));                            \
            atomicAdd(dstp + 2, bf16_to_f(V.z));                            \
            atomicAdd(dstp + 3, bf16_to_f(V.w));                            \
        }
        ACC1(E0, V0) ACC1(E1, V1) ACC1(E2, V2) ACC1(E3, V3)
#undef ACC1
    }
    __syncthreads();

    // writeout: 32 nodes x 512 bf16; coalesced us8 stores
    int nbase = tile * 32;
#pragma unroll
    for (int k = 0; k < 8; ++k) {
        int c = tid + k * 256;
        int nl = c >> 6;
        int node = nbase + nl;
        if (node < nNodes) {
            int rf = (c & 63) * 8;           // r*64 + f0
            int r = rf >> 6, f0 = rf & 63;
            const float* row = agf + ((r << 5) | nl) * AGSTRIDE + f0;
            us8 o;
#pragma unroll
            for (int j = 0; j < 8; ++j) o[j] = bf16_rne(row[j]);
            *(us8*)(agbf + (long)node * 512 + rf) = o;
        }
    }
}

// ---------------------------------------------------------------- MFMA einsum
__global__ __launch_bounds__(256) void einsum_kernel(
    const unsigned short* __restrict__ agbf, const unsigned short* __restrict__ wt,
    float* __restrict__ msgs, int nNodes)
{
    int wid = blockIdx.x * 4 + (threadIdx.x >> 6);
    int lane = threadIdx.x & 63;
    int nbase = wid * 32;
    if (nbase >= nNodes) return;
    int r16 = lane & 15;
    int kg  = lane >> 4;

    f32x4 acc[2][4];
#pragma unroll
    for (int m = 0; m < 2; ++m)
#pragma unroll
        for (int j = 0; j < 4; ++j) acc[m][j] = (f32x4){0.f, 0.f, 0.f, 0.f};

    int n0 = nbase + r16;      if (n0 >= nNodes) n0 = nNodes - 1;
    int n1 = nbase + 16 + r16; if (n1 >= nNodes) n1 = nNodes - 1;
    const unsigned short* a0p = agbf + (long)n0 * 512 + kg * 8;
    const unsigned short* a1p = agbf + (long)n1 * 512 + kg * 8;
    const unsigned short* bp  = wt + (long)r16 * 512 + kg * 8;

#pragma unroll 4
    for (int kk = 0; kk < 16; ++kk) {
        bf16x8 a0 = *(const bf16x8*)(a0p + kk * 32);
        bf16x8 a1 = *(const bf16x8*)(a1p + kk * 32);
#pragma unroll
        for (int j = 0; j < 4; ++j) {
            bf16x8 b = *(const bf16x8*)(bp + (long)j * 16 * 512 + kk * 32);
            acc[0][j] = __builtin_amdgcn_mfma_f32_16x16x32_bf16(a0, b, acc[0][j], 0, 0, 0);
            acc[1][j] = __builtin_amdgcn_mfma_f32_16x16x32_bf16(a1, b, acc[1][j], 0, 0, 0);
        }
    }

    // C layout (verified m89): col = lane&15, row = (lane>>4)*4 + reg
#pragma unroll
    for (int m = 0; m < 2; ++m) {
#pragma unroll
        for (int reg = 0; reg < 4; ++reg) {
            int row = nbase + m * 16 + kg * 4 + reg;
            if (row < nNodes) {
#pragma unroll
                for (int j = 0; j < 4; ++j)
                    msgs[(long)row * ND + j * 16 + r16] = acc[m][j][reg];
            }
        }
    }
}

// ---------------------------------------------------------------- MFMA MLP stage A
__global__ __launch_bounds__(256) void mlpA_kernel(
    const float* __restrict__ xin, const float* __restrict__ msgs,
    const float* __restrict__ eps, const unsigned short* __restrict__ wm1t,
    const float* __restrict__ mb1, unsigned short* __restrict__ tout, int nNodes)
{
    int wid = blockIdx.x * 4 + (threadIdx.x >> 6);
    int lane = threadIdx.x & 63;
    int nbase = wid * 32;
    if (nbase >= nNodes) return;
    int r16 = lane & 15;
    int kg  = lane >> 4;
    float epsv = 1.0f + eps[0];

    int n0 = nbase + r16;      if (n0 >= nNodes) n0 = nNodes - 1;
    int n1 = nbase + 16 + r16; if (n1 >= nNodes) n1 = nNodes - 1;

    bf16x8 afr[2][2];
#pragma unroll
    for (int m = 0; m < 2; ++m) {
        long nrow = (m == 0) ? n0 : n1;
#pragma unroll
        for (int kk = 0; kk < 2; ++kk) {
            long base = nrow * ND + kg * 8 + kk * 32;
            float4 x0 = *(const float4*)(xin + base);
            float4 x1 = *(const float4*)(xin + base + 4);
            float4 m0 = *(const float4*)(msgs + base);
            float4 m1 = *(const float4*)(msgs + base + 4);
            us8 u;
            u[0] = bf16_rne(fmaf(epsv, x0.x, m0.x));
            u[1] = bf16_rne(fmaf(epsv, x0.y, m0.y));
            u[2] = bf16_rne(fmaf(epsv, x0.z, m0.z));
            u[3] = bf16_rne(fmaf(epsv, x0.w, m0.w));
            u[4] = bf16_rne(fmaf(epsv, x1.x, m1.x));
            u[5] = bf16_rne(fmaf(epsv, x1.y, m1.y));
            u[6] = bf16_rne(fmaf(epsv, x1.z, m1.z));
            u[7] = bf16_rne(fmaf(epsv, x1.w, m1.w));
            afr[m][kk] = __builtin_bit_cast(bf16x8, u);
        }
    }

    f32x4 acc[2][4];
#pragma unroll
    for (int m = 0; m < 2; ++m)
#pragma unroll
        for (int j = 0; j < 4; ++j) acc[m][j] = (f32x4){0.f, 0.f, 0.f, 0.f};

#pragma unroll
    for (int kk = 0; kk < 2; ++kk) {
#pragma unroll
        for (int j = 0; j < 4; ++j) {
            bf16x8 b = *(const bf16x8*)(wm1t + (long)(j * 16 + r16) * ND + kg * 8 + kk * 32);
            acc[0][j] = __builtin_amdgcn_mfma_f32_16x16x32_bf16(afr[0][kk], b, acc[0][j], 0, 0, 0);
            acc[1][j] = __builtin_amdgcn_mfma_f32_16x16x32_bf16(afr[1][kk], b, acc[1][j], 0, 0, 0);
        }
    }

#pragma unroll
    for (int m = 0; m < 2; ++m) {
#pragma unroll
        for (int reg = 0; reg < 4; ++reg) {
            int row = nbase + m * 16 + kg * 4 + reg;
            if (row < nNodes) {
#pragma unroll
                for (int j = 0; j < 4; ++j) {
                    int col = j * 16 + r16;
                    float v = acc[m][j][reg] + mb1[col];
                    v = fmaxf(v, 0.f);
                    tout[(long)row * ND + col] = bf16_rne(v);
                }
            }
        }
    }
}

// ---------------------------------------------------------------- MFMA MLP stage B
__global__ __launch_bounds__(256) void mlpB_kernel(
    const unsigned short* __restrict__ tin, const unsigned short* __restrict__ wm2t,
    const float* __restrict__ mb2, const float* __restrict__ bias,
    float* __restrict__ out, unsigned short* __restrict__ out_bf, int nNodes)
{
    int wid = blockIdx.x * 4 + (threadIdx.x >> 6);
    int lane = threadIdx.x & 63;
    int nbase = wid * 32;
    if (nbase >= nNodes) return;
    int r16 = lane & 15;
    int kg  = lane >> 4;

    int n0 = nbase + r16;      if (n0 >= nNodes) n0 = nNodes - 1;
    int n1 = nbase + 16 + r16; if (n1 >= nNodes) n1 = nNodes - 1;
    const unsigned short* a0p = tin + (long)n0 * ND + kg * 8;
    const unsigned short* a1p = tin + (long)n1 * ND + kg * 8;

    f32x4 acc[2][4];
#pragma unroll
    for (int m = 0; m < 2; ++m)
#pragma unroll
        for (int j = 0; j < 4; ++j) acc[m][j] = (f32x4){0.f, 0.f, 0.f, 0.f};

#pragma unroll
    for (int kk = 0; kk < 2; ++kk) {
        bf16x8 a0 = *(const bf16x8*)(a0p + kk * 32);
        bf16x8 a1 = *(const bf16x8*)(a1p + kk * 32);
#pragma unroll
        for (int j = 0; j < 4; ++j) {
            bf16x8 b = *(const bf16x8*)(wm2t + (long)(j * 16 + r16) * ND + kg * 8 + kk * 32);
            acc[0][j] = __builtin_amdgcn_mfma_f32_16x16x32_bf16(a0, b, acc[0][j], 0, 0, 0);
            acc[1][j] = __builtin_amdgcn_mfma_f32_16x16x32_bf16(a1, b, acc[1][j], 0, 0, 0);
        }
    }

#pragma unroll
    for (int m = 0; m < 2; ++m) {
#pragma unroll
        for (int reg = 0; reg < 4; ++reg) {
            int row = nbase + m * 16 + kg * 4 + reg;
            if (row < nNodes) {
#pragma unroll
                for (int j = 0; j < 4; ++j) {
                    int col = j * 16 + r16;
                    float v = acc[m][j][reg] + mb2[col] + bias[col];
                    out[(long)row * ND + col] = v;
                    if (out_bf != nullptr)
                        out_bf[(long)row * ND + col] = bf16_rne(v);
                }
            }
        }
    }
}

// ---------------------------------------------------------------- launch
extern "C" void kernel_launch(void* const* d_in, const int* in_sizes, int n_in,
                              void* d_out, int out_size, void* d_ws, size_t ws_size,
                              hipStream_t stream) {
    const float* x    = (const float*)d_in[0];
    const int* esrc   = (const int*)d_in[1];
    const int* edst   = (const int*)d_in[2];
    const int* etyp   = (const int*)d_in[3];

    const float* W1   = (const float*)d_in[4];
    const float* b1   = (const float*)d_in[5];
    const float* e1   = (const float*)d_in[6];
    const float* m1w1 = (const float*)d_in[7];
    const float* m1b1 = (const float*)d_in[8];
    const float* m1w2 = (const float*)d_in[9];
    const float* m1b2 = (const float*)d_in[10];

    const float* W2   = (const float*)d_in[11];
    const float* b2   = (const float*)d_in[12];
    const float* e2   = (const float*)d_in[13];
    const float* m2w1 = (const float*)d_in[14];
    const float* m2b1 = (const float*)d_in[15];
    const float* m2w2 = (const float*)d_in[16];
    const float* m2b2 = (const float*)d_in[17];

    int nNodes = in_sizes[0] / ND;   // 50000
    int nEdges = in_sizes[1];        // 1600000
    int ntiles = (nNodes + 31) / 32; // 1563

    // ---- workspace layout (~104 MB)
    unsigned short* agbf = (unsigned short*)d_ws;                 // N*512 bf16 = 51.2MB
    float* msgs   = (float*)(agbf + (long)nNodes * 512);          // N*64 f32 = 12.8MB
    unsigned short* xhbf = (unsigned short*)(msgs + (long)nNodes * ND); // 6.4MB
    unsigned short* wt1  = xhbf + (long)nNodes * ND;
    unsigned short* wt2  = wt1 + 64 * 512;
    unsigned short* wm11 = wt2 + 64 * 512;
    unsigned short* wm12 = wm11 + 64 * 64;
    unsigned short* wm21 = wm12 + 64 * 64;
    unsigned short* wm22 = wm21 + 64 * 64;
    uint2* bbufA  = (uint2*)(wm22 + 64 * 64);                     // 8*CAPA*8B = 13.8MB
    uint2* bbufB  = bbufA + (long)NSLICE * CAPA;                  // 1568*1536*8B = 19.3MB
    int* cnts     = (int*)(bbufB + (long)NTILE_AL * CAPB);        // 8 + 1568
    int* bcur     = cnts;
    int* tilecur  = cnts + NSLICE;
    unsigned short* tbuf = (unsigned short*)bbufA;  // alias: bbufA dead after A2
    float* h    = (float*)d_out;   // layer-1 fp32 h aliases d_out
    float* outp = (float*)d_out;

    int esgrid = ((nNodes + 31) / 32 + 3) / 4;
    int n8 = nNodes * ND / 8;

    // ---- build tile buckets once (graph shared by both layers)
    zeroi_kernel<<<7, 256, 0, stream>>>(cnts, NSLICE + NTILE_AL);
    bucket8_kernel<<<782, 256, 0, stream>>>(esrc, edst, etyp, bcur, bbufA, nEdges);
    subbucket_kernel<<<320, 256, 0, stream>>>(bbufA, bcur, tilecur, bbufB);

    // ---- weight + x converts
    convw_kernel<<<128, 256, 0, stream>>>(W1, wt1);
    convw_kernel<<<128, 256, 0, stream>>>(W2, wt2);
    convm_kernel<<<16, 256, 0, stream>>>(m1w1, wm11);
    convm_kernel<<<16, 256, 0, stream>>>(m1w2, wm12);
    convm_kernel<<<16, 256, 0, stream>>>(m2w1, wm21);
    convm_kernel<<<16, 256, 0, stream>>>(m2w2, wm22);
    convx_kernel<<<(n8 + 255) / 256, 256, 0, stream>>>((const float4*)x, xhbf, n8);

    // ---- layer 1
    aggregate_kernel<<<ntiles, 256, 0, stream>>>(xhbf, bbufB, tilecur, agbf, nNodes);
    einsum_kernel<<<esgrid, 256, 0, stream>>>(agbf, wt1, msgs, nNodes);
    mlpA_kernel<<<esgrid, 256, 0, stream>>>(x, msgs, e1, wm11, m1b1, tbuf, nNodes);
    mlpB_kernel<<<esgrid, 256, 0, stream>>>(tbuf, wm12, m1b2, b1, h, xhbf, nNodes);

    // ---- layer 2
    aggregate_kernel<<<ntiles, 256, 0, stream>>>(xhbf, bbufB, tilecur, agbf, nNodes);
    einsum_kernel<<<esgrid, 256, 0, stream>>>(agbf, wt2, msgs, nNodes);
    mlpA_kernel<<<esgrid, 256, 0, stream>>>(h, msgs, e2, wm21, m2b1, tbuf, nNodes);
    mlpB_kernel<<<esgrid, 256, 0, stream>>>(tbuf, wm22, m2b2, b2, outp, nullptr, nNodes);
}

// Round 12
// 292.144 us; speedup vs baseline: 4.7868x; 4.7868x over previous
//
#include <hip/hip_runtime.h>

#define ND 64        // feature dim
#define NR 8         // num edge types
#define NSLICE 8     // dst slices (XCD count)
#define SLICE_NODES 6272   // 196*32; 8*6272 >= 50000
#define TPS 196      // tiles per slice (32 nodes each)
#define NTILE_AL 1568
#define CAPA 216064  // per-slice bucket capacity (mean 200704, ~35 sigma)
#define CAPB 1536    // per-tile bucket capacity (mean 1024, 16 sigma)

typedef __bf16 bf16x8 __attribute__((ext_vector_type(8)));
typedef float f32x4 __attribute__((ext_vector_type(4)));
typedef unsigned short us8 __attribute__((ext_vector_type(8)));

__device__ inline unsigned short bf16_rne(float f) {
    unsigned u = __float_as_uint(f);
    unsigned r = (u + 0x7FFFu + ((u >> 16) & 1u)) >> 16;
    return (unsigned short)r;
}
__device__ inline float bf16_to_f(unsigned short s) {
    return __uint_as_float(((unsigned)s) << 16);
}

// ---------------------------------------------------------------- zero ints
__global__ __launch_bounds__(256) void zeroi_kernel(int* __restrict__ p, int n) {
    int i = blockIdx.x * 256 + threadIdx.x;
    int stride = gridDim.x * 256;
    for (; i < n; i += stride) p[i] = 0;
}

// ---------------------------------------------------------------- A1: bucket edges into 8 dst-slices (proven R10)
__global__ __launch_bounds__(256) void bucket8_kernel(
    const int* __restrict__ src, const int* __restrict__ dst,
    const int* __restrict__ typ, int* __restrict__ bcur,
    uint2* __restrict__ bbufA, int nEdges)
{
    __shared__ uint2 outst[1024];
    __shared__ int lcnt[NSLICE];
    __shared__ int lbase[NSLICE];
    __shared__ int gbase[NSLICE];
    int tid = threadIdx.x;

    for (int base = blockIdx.x * 1024; base < nEdges; base += gridDim.x * 1024) {
        int bn = min(1024, nEdges - base);
        if (tid < NSLICE) lcnt[tid] = 0;
        __syncthreads();
        uint2 ent[4]; int eb[4], eo[4];
#pragma unroll
        for (int k = 0; k < 4; ++k) {
            int i = tid + k * 256;
            eb[k] = -1;
            if (i < bn) {
                int e = base + i;
                int d = dst[e];
                int s = d / SLICE_NODES;
                eb[k] = s;
                ent[k].x = (unsigned)src[e];
                ent[k].y = ((unsigned)s << 16) | ((unsigned)typ[e] << 13) |
                           (unsigned)(d - s * SLICE_NODES);
                eo[k] = atomicAdd(&lcnt[s], 1);
            }
        }
        __syncthreads();
        if (tid == 0) {
            int run = 0;
#pragma unroll
            for (int i = 0; i < NSLICE; ++i) { lbase[i] = run; run += lcnt[i]; }
        }
        if (tid < NSLICE && lcnt[tid] > 0) gbase[tid] = atomicAdd(&bcur[tid], lcnt[tid]);
        __syncthreads();
#pragma unroll
        for (int k = 0; k < 4; ++k)
            if (eb[k] >= 0) outst[lbase[eb[k]] + eo[k]] = ent[k];
        __syncthreads();
#pragma unroll
        for (int k = 0; k < 4; ++k) {
            int i = tid + k * 256;
            if (i < bn) {
                uint2 e = outst[i];
                int s = e.y >> 16;
                bbufA[(long)s * CAPA + gbase[s] + (i - lbase[s])] = e;
            }
        }
        __syncthreads();
    }
}

// ---------------------------------------------------------------- A2: per-slice re-bin into 196 node-tiles (proven R10)
__global__ __launch_bounds__(256) void subbucket_kernel(
    const uint2* __restrict__ bbufA, const int* __restrict__ bcur,
    int* __restrict__ tilecur, uint2* __restrict__ bbufB)
{
    __shared__ uint2 outst[2048];
    __shared__ int lcnt[TPS];
    __shared__ int lbase[TPS];
    __shared__ int gbase[TPS];
    __shared__ int scanbuf[256];
    int tid = threadIdx.x;
    int slice = blockIdx.x & 7;
    int chunk = blockIdx.x >> 3;
    int nchunk = gridDim.x >> 3;
    int n = bcur[slice];
    const uint2* in = bbufA + (long)slice * CAPA;
    int per = (n + nchunk - 1) / nchunk;
    int beg = chunk * per;
    int end = min(beg + per, n);

    for (int b0 = beg; b0 < end; b0 += 2048) {
        int bn = min(2048, end - b0);
        if (tid < TPS) lcnt[tid] = 0;
        __syncthreads();
        uint2 ent[8]; int eb[8], eo[8];
#pragma unroll
        for (int k = 0; k < 8; ++k) {
            int i = tid + k * 256;
            eb[k] = -1;
            if (i < bn) {
                ent[k] = in[b0 + i];
                int bin = (ent[k].y & 8191u) >> 5;
                eb[k] = bin;
                eo[k] = atomicAdd(&lcnt[bin], 1);
            }
        }
        __syncthreads();
        int v = (tid < TPS) ? lcnt[tid] : 0;
        scanbuf[tid] = v;
        __syncthreads();
        int xs = v;
        for (int off = 1; off < 256; off <<= 1) {
            int y = (tid >= off) ? scanbuf[tid - off] : 0;
            __syncthreads();
            xs += y;
            scanbuf[tid] = xs;
            __syncthreads();
        }
        if (tid < TPS) {
            lbase[tid] = xs - v;
            if (v > 0) gbase[tid] = atomicAdd(&tilecur[slice * TPS + tid], v);
        }
        __syncthreads();
#pragma unroll
        for (int k = 0; k < 8; ++k)
            if (eb[k] >= 0) outst[lbase[eb[k]] + eo[k]] = ent[k];
        __syncthreads();
#pragma unroll
        for (int k = 0; k < 8; ++k) {
            int i = tid + k * 256;
            if (i < bn) {
                uint2 e = outst[i];
                int bin = (e.y & 8191u) >> 5;
                bbufB[(long)(slice * TPS + bin) * CAPB + gbase[bin] + (i - lbase[bin])] = e;
            }
        }
        __syncthreads();
    }
}

// ---------------------------------------------------------------- tilescan: prefix over per-tile counts (1 block)
__global__ __launch_bounds__(256) void tilescan_kernel(
    const int* __restrict__ tilecur, int* __restrict__ tilebase,
    int* __restrict__ offsets, int ntAl, int ntUsed, int nEdges)
{
    __shared__ int lds[256];
    int tid = threadIdx.x;
    int v[7]; int lsum = 0;
#pragma unroll
    for (int k = 0; k < 7; ++k) {
        int i = tid * 7 + k;
        v[k] = (i < ntAl) ? tilecur[i] : 0;
        lsum += v[k];
    }
    lds[tid] = lsum;
    __syncthreads();
    int x = lsum;
    for (int off = 1; off < 256; off <<= 1) {
        int y = (tid >= off) ? lds[tid - off] : 0;
        __syncthreads();
        x += y;
        lds[tid] = x;
        __syncthreads();
    }
    int run = x - lsum;
#pragma unroll
    for (int k = 0; k < 7; ++k) {
        int i = tid * 7 + k;
        if (i < ntAl) tilebase[i] = run;
        run += v[k];
    }
    if (tid == 0) offsets[(long)ntUsed * 256] = nEdges;  // sentinel end
}

// ---------------------------------------------------------------- tilesort: per-tile LDS counting sort -> CSR
// Block per 32-node tile: count 256 (r,nl) bins in LDS, scan, scatter src ids
// to LDS, then DENSE coalesced writes of offsets (256 ints) and perm (n ints).
// No scattered global stores -> no 64B/store write amplification.
__global__ __launch_bounds__(256) void tilesort_kernel(
    const uint2* __restrict__ bbufB, const int* __restrict__ tilecur,
    const int* __restrict__ tilebase, int* __restrict__ offsets,
    int* __restrict__ perm)
{
    __shared__ int outst[CAPB];
    __shared__ int lcnt[256];
    __shared__ int sbuf[256];
    __shared__ int cur[256];
    int t = blockIdx.x;
    int tid = threadIdx.x;
    int n = tilecur[t];
    int base = tilebase[t];
    const uint2* buf = bbufB + (long)t * CAPB;

    lcnt[tid] = 0;
    __syncthreads();
    for (int i = tid; i < n; i += 256) {
        uint2 e = buf[i];
        int k = (((e.y >> 13) & 7) << 5) | (e.y & 31);   // r*32 + nl
        atomicAdd(&lcnt[k], 1);
    }
    __syncthreads();
    int v = lcnt[tid];
    sbuf[tid] = v;
    __syncthreads();
    int x = v;
    for (int off = 1; off < 256; off <<= 1) {
        int y = (tid >= off) ? sbuf[tid - off] : 0;
        __syncthreads();
        x += y;
        sbuf[tid] = x;
        __syncthreads();
    }
    int pfx = x - v;
    cur[tid] = pfx;
    offsets[(long)t * 256 + tid] = base + pfx;
    __syncthreads();
    for (int i = tid; i < n; i += 256) {
        uint2 e = buf[i];
        int k = (((e.y >> 13) & 7) << 5) | (e.y & 31);
        int pos = atomicAdd(&cur[k], 1);
        outst[pos] = (int)e.x;
    }
    __syncthreads();
    for (int i = tid; i < n; i += 256) perm[base + i] = outst[i];
}

// ---------------------------------------------------------------- weight convert+transpose (relation W)
__global__ __launch_bounds__(256) void convw_kernel(
    const float* __restrict__ W, unsigned short* __restrict__ wt)
{
    int idx = blockIdx.x * 256 + threadIdx.x;
    if (idx >= 64 * 512) return;
    int o = idx >> 9, k = idx & 511;
    wt[idx] = bf16_rne(W[(long)k * 64 + o]);
}

// ---------------------------------------------------------------- MLP weight convert+transpose
__global__ __launch_bounds__(256) void convm_kernel(
    const float* __restrict__ m, unsigned short* __restrict__ wmt)
{
    int idx = blockIdx.x * 256 + threadIdx.x;
    if (idx >= 64 * 64) return;
    int o = idx >> 6, k = idx & 63;
    wmt[idx] = bf16_rne(m[k * 64 + o]);
}

// ---------------------------------------------------------------- x -> bf16
__global__ __launch_bounds__(256) void convx_kernel(
    const float4* __restrict__ x, unsigned short* __restrict__ xb, int n8)
{
    int i = blockIdx.x * 256 + threadIdx.x;
    if (i >= n8) return;
    float4 v0 = x[i * 2], v1 = x[i * 2 + 1];
    us8 o;
    o[0] = bf16_rne(v0.x); o[1] = bf16_rne(v0.y);
    o[2] = bf16_rne(v0.z); o[3] = bf16_rne(v0.w);
    o[4] = bf16_rne(v1.x); o[5] = bf16_rne(v1.y);
    o[6] = bf16_rne(v1.z); o[7] = bf16_rne(v1.w);
    *(us8*)(xb + (long)i * 8) = o;
}

// ---------------------------------------------------------------- gather (R9 kernel; new seg->(node,r) mapping)
// 16 lanes per segment; lane owns 4 features (ushort4 = 8B/lane);
// 4 segments per wave, grid-stride persistent.
__global__ __launch_bounds__(256) void gather_kernel(
    const unsigned short* __restrict__ xb, const int* __restrict__ offsets,
    const int* __restrict__ perm, unsigned short* __restrict__ agbf,
    int Stot, int nNodes)
{
    int tid = threadIdx.x;
    int gidx = (blockIdx.x * 256 + tid) >> 4;
    int nGroups = (gridDim.x * 256) >> 4;
    int fl = tid & 15;

    for (int s = gidx; s < Stot; s += nGroups) {
        int t = s >> 8, k = s & 255;
        int node = (t << 5) | (k & 31);
        if (node >= nNodes) continue;
        int r = k >> 5;
        int beg = offsets[s], end = offsets[s + 1];
        float a0 = 0.f, a1 = 0.f, a2 = 0.f, a3 = 0.f;
        for (int p = beg; p < end; ++p) {
            int srcn = perm[p];
            ushort4 vv = *(const ushort4*)(xb + (long)srcn * ND + fl * 4);
            a0 += bf16_to_f(vv.x); a1 += bf16_to_f(vv.y);
            a2 += bf16_to_f(vv.z); a3 += bf16_to_f(vv.w);
        }
        ushort4 o;
        o.x = bf16_rne(a0); o.y = bf16_rne(a1);
        o.z = bf16_rne(a2); o.w = bf16_rne(a3);
        *(ushort4*)(agbf + (long)node * 512 + r * ND + fl * 4) = o;
    }
}

// ---------------------------------------------------------------- MFMA einsum
__global__ __launch_bounds__(256) void einsum_kernel(
    const unsigned short* __restrict__ agbf, const unsigned short* __restrict__ wt,
    float* __restrict__ msgs, int nNodes)
{
    int wid = blockIdx.x * 4 + (threadIdx.x >> 6);
    int lane = threadIdx.x & 63;
    int nbase = wid * 32;
    if (nbase >= nNodes) return;
    int r16 = lane & 15;
    int kg  = lane >> 4;

    f32x4 acc[2][4];
#pragma unroll
    for (int m = 0; m < 2; ++m)
#pragma unroll
        for (int j = 0; j < 4; ++j) acc[m][j] = (f32x4){0.f, 0.f, 0.f, 0.f};

    int n0 = nbase + r16;      if (n0 >= nNodes) n0 = nNodes - 1;
    int n1 = nbase + 16 + r16; if (n1 >= nNodes) n1 = nNodes - 1;
    const unsigned short* a0p = agbf + (long)n0 * 512 + kg * 8;
    const unsigned short* a1p = agbf + (long)n1 * 512 + kg * 8;
    const unsigned short* bp  = wt + (long)r16 * 512 + kg * 8;

#pragma unroll 4
    for (int kk = 0; kk < 16; ++kk) {
        bf16x8 a0 = *(const bf16x8*)(a0p + kk * 32);
        bf16x8 a1 = *(const bf16x8*)(a1p + kk * 32);
#pragma unroll
        for (int j = 0; j < 4; ++j) {
            bf16x8 b = *(const bf16x8*)(bp + (long)j * 16 * 512 + kk * 32);
            acc[0][j] = __builtin_amdgcn_mfma_f32_16x16x32_bf16(a0, b, acc[0][j], 0, 0, 0);
            acc[1][j] = __builtin_amdgcn_mfma_f32_16x16x32_bf16(a1, b, acc[1][j], 0, 0, 0);
        }
    }

    // C layout (verified m89): col = lane&15, row = (lane>>4)*4 + reg
#pragma unroll
    for (int m = 0; m < 2; ++m) {
#pragma unroll
        for (int reg = 0; reg < 4; ++reg) {
            int row = nbase + m * 16 + kg * 4 + reg;
            if (row < nNodes) {
#pragma unroll
                for (int j = 0; j < 4; ++j)
                    msgs[(long)row * ND + j * 16 + r16] = acc[m][j][reg];
            }
        }
    }
}

// ---------------------------------------------------------------- MFMA MLP stage A
__global__ __launch_bounds__(256) void mlpA_kernel(
    const float* __restrict__ xin, const float* __restrict__ msgs,
    const float* __restrict__ eps, const unsigned short* __restrict__ wm1t,
    const float* __restrict__ mb1, unsigned short* __restrict__ tout, int nNodes)
{
    int wid = blockIdx.x * 4 + (threadIdx.x >> 6);
    int lane = threadIdx.x & 63;
    int nbase = wid * 32;
    if (nbase >= nNodes) return;
    int r16 = lane & 15;
    int kg  = lane >> 4;
    float epsv = 1.0f + eps[0];

    int n0 = nbase + r16;      if (n0 >= nNodes) n0 = nNodes - 1;
    int n1 = nbase + 16 + r16; if (n1 >= nNodes) n1 = nNodes - 1;

    bf16x8 afr[2][2];
#pragma unroll
    for (int m = 0; m < 2; ++m) {
        long nrow = (m == 0) ? n0 : n1;
#pragma unroll
        for (int kk = 0; kk < 2; ++kk) {
            long base = nrow * ND + kg * 8 + kk * 32;
            float4 x0 = *(const float4*)(xin + base);
            float4 x1 = *(const float4*)(xin + base + 4);
            float4 m0 = *(const float4*)(msgs + base);
            float4 m1 = *(const float4*)(msgs + base + 4);
            us8 u;
            u[0] = bf16_rne(fmaf(epsv, x0.x, m0.x));
            u[1] = bf16_rne(fmaf(epsv, x0.y, m0.y));
            u[2] = bf16_rne(fmaf(epsv, x0.z, m0.z));
            u[3] = bf16_rne(fmaf(epsv, x0.w, m0.w));
            u[4] = bf16_rne(fmaf(epsv, x1.x, m1.x));
            u[5] = bf16_rne(fmaf(epsv, x1.y, m1.y));
            u[6] = bf16_rne(fmaf(epsv, x1.z, m1.z));
            u[7] = bf16_rne(fmaf(epsv, x1.w, m1.w));
            afr[m][kk] = __builtin_bit_cast(bf16x8, u);
        }
    }

    f32x4 acc[2][4];
#pragma unroll
    for (int m = 0; m < 2; ++m)
#pragma unroll
        for (int j = 0; j < 4; ++j) acc[m][j] = (f32x4){0.f, 0.f, 0.f, 0.f};

#pragma unroll
    for (int kk = 0; kk < 2; ++kk) {
#pragma unroll
        for (int j = 0; j < 4; ++j) {
            bf16x8 b = *(const bf16x8*)(wm1t + (long)(j * 16 + r16) * ND + kg * 8 + kk * 32);
            acc[0][j] = __builtin_amdgcn_mfma_f32_16x16x32_bf16(afr[0][kk], b, acc[0][j], 0, 0, 0);
            acc[1][j] = __builtin_amdgcn_mfma_f32_16x16x32_bf16(afr[1][kk], b, acc[1][j], 0, 0, 0);
        }
    }

#pragma unroll
    for (int m = 0; m < 2; ++m) {
#pragma unroll
        for (int reg = 0; reg < 4; ++reg) {
            int row = nbase + m * 16 + kg * 4 + reg;
            if (row < nNodes) {
#pragma unroll
                for (int j = 0; j < 4; ++j) {
                    int col = j * 16 + r16;
                    float v = acc[m][j][reg] + mb1[col];
                    v = fmaxf(v, 0.f);
                    tout[(long)row * ND + col] = bf16_rne(v);
                }
            }
        }
    }
}

// ---------------------------------------------------------------- MFMA MLP stage B
__global__ __launch_bounds__(256) void mlpB_kernel(
    const unsigned short* __restrict__ tin, const unsigned short* __restrict__ wm2t,
    const float* __restrict__ mb2, const float* __restrict__ bias,
    float* __restrict__ out, unsigned short* __restrict__ out_bf, int nNodes)
{
    int wid = blockIdx.x * 4 + (threadIdx.x >> 6);
    int lane = threadIdx.x & 63;
    int nbase = wid * 32;
    if (nbase >= nNodes) return;
    int r16 = lane & 15;
    int kg  = lane >> 4;

    int n0 = nbase + r16;      if (n0 >= nNodes) n0 = nNodes - 1;
    int n1 = nbase + 16 + r16; if (n1 >= nNodes) n1 = nNodes - 1;
    const unsigned short* a0p = tin + (long)n0 * ND + kg * 8;
    const unsigned short* a1p = tin + (long)n1 * ND + kg * 8;

    f32x4 acc[2][4];
#pragma unroll
    for (int m = 0; m < 2; ++m)
#pragma unroll
        for (int j = 0; j < 4; ++j) acc[m][j] = (f32x4){0.f, 0.f, 0.f, 0.f};

#pragma unroll
    for (int kk = 0; kk < 2; ++kk) {
        bf16x8 a0 = *(const bf16x8*)(a0p + kk * 32);
        bf16x8 a1 = *(const bf16x8*)(a1p + kk * 32);
#pragma unroll
        for (int j = 0; j < 4; ++j) {
            bf16x8 b = *(const bf16x8*)(wm2t + (long)(j * 16 + r16) * ND + kg * 8 + kk * 32);
            acc[0][j] = __builtin_amdgcn_mfma_f32_16x16x32_bf16(a0, b, acc[0][j], 0, 0, 0);
            acc[1][j] = __builtin_amdgcn_mfma_f32_16x16x32_bf16(a1, b, acc[1][j], 0, 0, 0);
        }
    }

#pragma unroll
    for (int m = 0; m < 2; ++m) {
#pragma unroll
        for (int reg = 0; reg < 4; ++reg) {
            int row = nbase + m * 16 + kg * 4 + reg;
            if (row < nNodes) {
#pragma unroll
                for (int j = 0; j < 4; ++j) {
                    int col = j * 16 + r16;
                    float v = acc[m][j][reg] + mb2[col] + bias[col];
                    out[(long)row * ND + col] = v;
                    if (out_bf != nullptr)
                        out_bf[(long)row * ND + col] = bf16_rne(v);
                }
            }
        }
    }
}

// ---------------------------------------------------------------- launch
extern "C" void kernel_launch(void* const* d_in, const int* in_sizes, int n_in,
                              void* d_out, int out_size, void* d_ws, size_t ws_size,
                              hipStream_t stream) {
    const float* x    = (const float*)d_in[0];
    const int* esrc   = (const int*)d_in[1];
    const int* edst   = (const int*)d_in[2];
    const int* etyp   = (const int*)d_in[3];

    const float* W1   = (const float*)d_in[4];
    const float* b1   = (const float*)d_in[5];
    const float* e1   = (const float*)d_in[6];
    const float* m1w1 = (const float*)d_in[7];
    const float* m1b1 = (const float*)d_in[8];
    const float* m1w2 = (const float*)d_in[9];
    const float* m1b2 = (const float*)d_in[10];

    const float* W2   = (const float*)d_in[11];
    const float* b2   = (const float*)d_in[12];
    const float* e2   = (const float*)d_in[13];
    const float* m2w1 = (const float*)d_in[14];
    const float* m2b1 = (const float*)d_in[15];
    const float* m2w2 = (const float*)d_in[16];
    const float* m2b2 = (const float*)d_in[17];

    int nNodes = in_sizes[0] / ND;   // 50000
    int nEdges = in_sizes[1];        // 1600000
    int ntiles = (nNodes + 31) / 32; // 1563
    int Stot = ntiles * 256;         // 400128 segments (incl. padding nodes)

    // ---- workspace layout (~112 MB)
    unsigned short* agbf = (unsigned short*)d_ws;                 // N*512 bf16 = 51.2MB
    float* msgs   = (float*)(agbf + (long)nNodes * 512);          // N*64 f32 = 12.8MB
    unsigned short* xhbf = (unsigned short*)(msgs + (long)nNodes * ND); // 6.4MB
    unsigned short* wt1  = xhbf + (long)nNodes * ND;
    unsigned short* wt2  = wt1 + 64 * 512;
    unsigned short* wm11 = wt2 + 64 * 512;
    unsigned short* wm12 = wm11 + 64 * 64;
    unsigned short* wm21 = wm12 + 64 * 64;
    unsigned short* wm22 = wm21 + 64 * 64;
    uint2* bbufA  = (uint2*)(wm22 + 64 * 64);                     // 13.8MB
    uint2* bbufB  = bbufA + (long)NSLICE * CAPA;                  // 19.3MB
    int* cnts     = (int*)(bbufB + (long)NTILE_AL * CAPB);
    int* bcur     = cnts;                                         // 8
    int* tilecur  = cnts + NSLICE;                                // 1568
    int* tilebase = tilecur + NTILE_AL;                           // 1568
    int* offsets  = tilebase + NTILE_AL;                          // Stot+1
    int* perm     = offsets + (Stot + 256);                       // E ints = 6.4MB
    unsigned short* tbuf = (unsigned short*)bbufA;  // alias: bbufA dead after tilesort
    float* h    = (float*)d_out;   // layer-1 fp32 h aliases d_out
    float* outp = (float*)d_out;

    int esgrid = ((nNodes + 31) / 32 + 3) / 4;
    int n8 = nNodes * ND / 8;

    // ---- build per-segment CSR via LDS-staged two-level bucketing (all dense writes)
    zeroi_kernel<<<7, 256, 0, stream>>>(cnts, NSLICE + NTILE_AL);
    bucket8_kernel<<<782, 256, 0, stream>>>(esrc, edst, etyp, bcur, bbufA, nEdges);
    subbucket_kernel<<<320, 256, 0, stream>>>(bbufA, bcur, tilecur, bbufB);
    tilescan_kernel<<<1, 256, 0, stream>>>(tilecur, tilebase, offsets, NTILE_AL, ntiles, nEdges);
    tilesort_kernel<<<ntiles, 256, 0, stream>>>(bbufB, tilecur, tilebase, offsets, perm);

    // ---- weight + x converts
    convw_kernel<<<128, 256, 0, stream>>>(W1, wt1);
    convw_kernel<<<128, 256, 0, stream>>>(W2, wt2);
    convm_kernel<<<16, 256, 0, stream>>>(m1w1, wm11);
    convm_kernel<<<16, 256, 0, stream>>>(m1w2, wm12);
    convm_kernel<<<16, 256, 0, stream>>>(m2w1, wm21);
    convm_kernel<<<16, 256, 0, stream>>>(m2w2, wm22);
    convx_kernel<<<(n8 + 255) / 256, 256, 0, stream>>>((const float4*)x, xhbf, n8);

    // ---- layer 1
    gather_kernel<<<2048, 256, 0, stream>>>(xhbf, offsets, perm, agbf, Stot, nNodes);
    einsum_kernel<<<esgrid, 256, 0, stream>>>(agbf, wt1, msgs, nNodes);
    mlpA_kernel<<<esgrid, 256, 0, stream>>>(x, msgs, e1, wm11, m1b1, tbuf, nNodes);
    mlpB_kernel<<<esgrid, 256, 0, stream>>>(tbuf, wm12, m1b2, b1, h, xhbf, nNodes);

    // ---- layer 2
    gather_kernel<<<2048, 256, 0, stream>>>(xhbf, offsets, perm, agbf, Stot, nNodes);
    einsum_kernel<<<esgrid, 256, 0, stream>>>(agbf, wt2, msgs, nNodes);
    mlpA_kernel<<<esgrid, 256, 0, stream>>>(h, msgs, e2, wm21, m2b1, tbuf, nNodes);
    mlpB_kernel<<<esgrid, 256, 0, stream>>>(tbuf, wm22, m2b2, b2, outp, nullptr, nNodes);
}

// Round 13
// 260.617 us; speedup vs baseline: 5.3658x; 1.1210x over previous
//
#include <hip/hip_runtime.h>

#define ND 64        // feature dim
#define NR 8         // num edge types
#define NSLICE 8     // dst slices (XCD count)
#define SLICE_NODES 6272   // 196*32; 8*6272 >= 50000
#define TPS 196      // tiles per slice (32 nodes each)
#define NTILE_AL 1568
#define CAPA 216064  // per-slice bucket capacity (mean 200704, ~35 sigma)
#define CAPB 1536    // per-tile bucket capacity (mean 1024, 16 sigma)
#define LPAD 66      // LDS transpose row stride (bank-conflict-free)

typedef __bf16 bf16x8 __attribute__((ext_vector_type(8)));
typedef float f32x4 __attribute__((ext_vector_type(4)));
typedef unsigned short us8 __attribute__((ext_vector_type(8)));

__device__ inline unsigned short bf16_rne(float f) {
    unsigned u = __float_as_uint(f);
    unsigned r = (u + 0x7FFFu + ((u >> 16) & 1u)) >> 16;
    return (unsigned short)r;
}
__device__ inline float bf16_to_f(unsigned short s) {
    return __uint_as_float(((unsigned)s) << 16);
}

// ---------------------------------------------------------------- zero ints
__global__ __launch_bounds__(256) void zeroi_kernel(int* __restrict__ p, int n) {
    int i = blockIdx.x * 256 + threadIdx.x;
    int stride = gridDim.x * 256;
    for (; i < n; i += stride) p[i] = 0;
}

// ---------------------------------------------------------------- A1: bucket edges into 8 dst-slices (proven R10)
__global__ __launch_bounds__(256) void bucket8_kernel(
    const int* __restrict__ src, const int* __restrict__ dst,
    const int* __restrict__ typ, int* __restrict__ bcur,
    uint2* __restrict__ bbufA, int nEdges)
{
    __shared__ uint2 outst[1024];
    __shared__ int lcnt[NSLICE];
    __shared__ int lbase[NSLICE];
    __shared__ int gbase[NSLICE];
    int tid = threadIdx.x;

    for (int base = blockIdx.x * 1024; base < nEdges; base += gridDim.x * 1024) {
        int bn = min(1024, nEdges - base);
        if (tid < NSLICE) lcnt[tid] = 0;
        __syncthreads();
        uint2 ent[4]; int eb[4], eo[4];
#pragma unroll
        for (int k = 0; k < 4; ++k) {
            int i = tid + k * 256;
            eb[k] = -1;
            if (i < bn) {
                int e = base + i;
                int d = dst[e];
                int s = d / SLICE_NODES;
                eb[k] = s;
                ent[k].x = (unsigned)src[e];
                ent[k].y = ((unsigned)s << 16) | ((unsigned)typ[e] << 13) |
                           (unsigned)(d - s * SLICE_NODES);
                eo[k] = atomicAdd(&lcnt[s], 1);
            }
        }
        __syncthreads();
        if (tid == 0) {
            int run = 0;
#pragma unroll
            for (int i = 0; i < NSLICE; ++i) { lbase[i] = run; run += lcnt[i]; }
        }
        if (tid < NSLICE && lcnt[tid] > 0) gbase[tid] = atomicAdd(&bcur[tid], lcnt[tid]);
        __syncthreads();
#pragma unroll
        for (int k = 0; k < 4; ++k)
            if (eb[k] >= 0) outst[lbase[eb[k]] + eo[k]] = ent[k];
        __syncthreads();
#pragma unroll
        for (int k = 0; k < 4; ++k) {
            int i = tid + k * 256;
            if (i < bn) {
                uint2 e = outst[i];
                int s = e.y >> 16;
                bbufA[(long)s * CAPA + gbase[s] + (i - lbase[s])] = e;
            }
        }
        __syncthreads();
    }
}

// ---------------------------------------------------------------- A2: per-slice re-bin into 196 node-tiles (proven R10)
__global__ __launch_bounds__(256) void subbucket_kernel(
    const uint2* __restrict__ bbufA, const int* __restrict__ bcur,
    int* __restrict__ tilecur, uint2* __restrict__ bbufB)
{
    __shared__ uint2 outst[2048];
    __shared__ int lcnt[TPS];
    __shared__ int lbase[TPS];
    __shared__ int gbase[TPS];
    __shared__ int scanbuf[256];
    int tid = threadIdx.x;
    int slice = blockIdx.x & 7;
    int chunk = blockIdx.x >> 3;
    int nchunk = gridDim.x >> 3;
    int n = bcur[slice];
    const uint2* in = bbufA + (long)slice * CAPA;
    int per = (n + nchunk - 1) / nchunk;
    int beg = chunk * per;
    int end = min(beg + per, n);

    for (int b0 = beg; b0 < end; b0 += 2048) {
        int bn = min(2048, end - b0);
        if (tid < TPS) lcnt[tid] = 0;
        __syncthreads();
        uint2 ent[8]; int eb[8], eo[8];
#pragma unroll
        for (int k = 0; k < 8; ++k) {
            int i = tid + k * 256;
            eb[k] = -1;
            if (i < bn) {
                ent[k] = in[b0 + i];
                int bin = (ent[k].y & 8191u) >> 5;
                eb[k] = bin;
                eo[k] = atomicAdd(&lcnt[bin], 1);
            }
        }
        __syncthreads();
        int v = (tid < TPS) ? lcnt[tid] : 0;
        scanbuf[tid] = v;
        __syncthreads();
        int xs = v;
        for (int off = 1; off < 256; off <<= 1) {
            int y = (tid >= off) ? scanbuf[tid - off] : 0;
            __syncthreads();
            xs += y;
            scanbuf[tid] = xs;
            __syncthreads();
        }
        if (tid < TPS) {
            lbase[tid] = xs - v;
            if (v > 0) gbase[tid] = atomicAdd(&tilecur[slice * TPS + tid], v);
        }
        __syncthreads();
#pragma unroll
        for (int k = 0; k < 8; ++k)
            if (eb[k] >= 0) outst[lbase[eb[k]] + eo[k]] = ent[k];
        __syncthreads();
#pragma unroll
        for (int k = 0; k < 8; ++k) {
            int i = tid + k * 256;
            if (i < bn) {
                uint2 e = outst[i];
                int bin = (e.y & 8191u) >> 5;
                bbufB[(long)(slice * TPS + bin) * CAPB + gbase[bin] + (i - lbase[bin])] = e;
            }
        }
        __syncthreads();
    }
}

// ---------------------------------------------------------------- tilescan: prefix over per-tile counts (1 block)
__global__ __launch_bounds__(256) void tilescan_kernel(
    const int* __restrict__ tilecur, int* __restrict__ tilebase,
    int* __restrict__ offsets, int ntAl, int ntUsed, int nEdges)
{
    __shared__ int lds[256];
    int tid = threadIdx.x;
    int v[7]; int lsum = 0;
#pragma unroll
    for (int k = 0; k < 7; ++k) {
        int i = tid * 7 + k;
        v[k] = (i < ntAl) ? tilecur[i] : 0;
        lsum += v[k];
    }
    lds[tid] = lsum;
    __syncthreads();
    int x = lsum;
    for (int off = 1; off < 256; off <<= 1) {
        int y = (tid >= off) ? lds[tid - off] : 0;
        __syncthreads();
        x += y;
        lds[tid] = x;
        __syncthreads();
    }
    int run = x - lsum;
#pragma unroll
    for (int k = 0; k < 7; ++k) {
        int i = tid * 7 + k;
        if (i < ntAl) tilebase[i] = run;
        run += v[k];
    }
    if (tid == 0) offsets[(long)ntUsed * 256] = nEdges;  // sentinel end
}

// ---------------------------------------------------------------- tilesort: per-tile LDS counting sort -> CSR
__global__ __launch_bounds__(256) void tilesort_kernel(
    const uint2* __restrict__ bbufB, const int* __restrict__ tilecur,
    const int* __restrict__ tilebase, int* __restrict__ offsets,
    int* __restrict__ perm)
{
    __shared__ int outst[CAPB];
    __shared__ int lcnt[256];
    __shared__ int sbuf[256];
    __shared__ int cur[256];
    int t = blockIdx.x;
    int tid = threadIdx.x;
    int n = tilecur[t];
    int base = tilebase[t];
    const uint2* buf = bbufB + (long)t * CAPB;

    lcnt[tid] = 0;
    __syncthreads();
    for (int i = tid; i < n; i += 256) {
        uint2 e = buf[i];
        int k = (((e.y >> 13) & 7) << 5) | (e.y & 31);   // r*32 + nl
        atomicAdd(&lcnt[k], 1);
    }
    __syncthreads();
    int v = lcnt[tid];
    sbuf[tid] = v;
    __syncthreads();
    int x = v;
    for (int off = 1; off < 256; off <<= 1) {
        int y = (tid >= off) ? sbuf[tid - off] : 0;
        __syncthreads();
        x += y;
        sbuf[tid] = x;
        __syncthreads();
    }
    int pfx = x - v;
    cur[tid] = pfx;
    offsets[(long)t * 256 + tid] = base + pfx;
    __syncthreads();
    for (int i = tid; i < n; i += 256) {
        uint2 e = buf[i];
        int k = (((e.y >> 13) & 7) << 5) | (e.y & 31);
        int pos = atomicAdd(&cur[k], 1);
        outst[pos] = (int)e.x;
    }
    __syncthreads();
    for (int i = tid; i < n; i += 256) perm[base + i] = outst[i];
}

// ---------------------------------------------------------------- convert_all: wt1|wt2|wm11|wm12|wm21|wm22|xhbf in one launch
__global__ __launch_bounds__(256) void convert_all_kernel(
    const float* __restrict__ W1, const float* __restrict__ W2,
    const float* __restrict__ m1w1, const float* __restrict__ m1w2,
    const float* __restrict__ m2w1, const float* __restrict__ m2w2,
    const float4* __restrict__ x,
    unsigned short* __restrict__ wt1, unsigned short* __restrict__ wt2,
    unsigned short* __restrict__ wm11, unsigned short* __restrict__ wm12,
    unsigned short* __restrict__ wm21, unsigned short* __restrict__ wm22,
    unsigned short* __restrict__ xb, int n8)
{
    int idx = blockIdx.x * 256 + threadIdx.x;
    if (idx < 65536) {                      // wt: [64 o][512 k] = W[k][o]
        const float* W = (idx < 32768) ? W1 : W2;
        unsigned short* wt = (idx < 32768) ? wt1 : wt2;
        int i = idx & 32767;
        int o = i >> 9, k = i & 511;
        wt[i] = bf16_rne(W[(long)k * 64 + o]);
        return;
    }
    idx -= 65536;
    if (idx < 16384) {                      // wm: [64 o][64 k] = m[k][o]
        int which = idx >> 12;
        const float* m = (which == 0) ? m1w1 : (which == 1) ? m1w2
                       : (which == 2) ? m2w1 : m2w2;
        unsigned short* wm = (which == 0) ? wm11 : (which == 1) ? wm12
                           : (which == 2) ? wm21 : wm22;
        int i = idx & 4095;
        int o = i >> 6, k = i & 63;
        wm[i] = bf16_rne(m[k * 64 + o]);
        return;
    }
    idx -= 16384;
    if (idx < n8) {                         // x -> bf16 (8 elems/thread)
        float4 v0 = x[idx * 2], v1 = x[idx * 2 + 1];
        us8 o;
        o[0] = bf16_rne(v0.x); o[1] = bf16_rne(v0.y);
        o[2] = bf16_rne(v0.z); o[3] = bf16_rne(v0.w);
        o[4] = bf16_rne(v1.x); o[5] = bf16_rne(v1.y);
        o[6] = bf16_rne(v1.z); o[7] = bf16_rne(v1.w);
        *(us8*)(xb + (long)idx * 8) = o;
    }
}

// ---------------------------------------------------------------- gather (unchanged from R12)
__global__ __launch_bounds__(256) void gather_kernel(
    const unsigned short* __restrict__ xb, const int* __restrict__ offsets,
    const int* __restrict__ perm, unsigned short* __restrict__ agbf,
    int Stot, int nNodes)
{
    int tid = threadIdx.x;
    int gidx = (blockIdx.x * 256 + tid) >> 4;
    int nGroups = (gridDim.x * 256) >> 4;
    int fl = tid & 15;

    for (int s = gidx; s < Stot; s += nGroups) {
        int t = s >> 8, k = s & 255;
        int node = (t << 5) | (k & 31);
        if (node >= nNodes) continue;
        int r = k >> 5;
        int beg = offsets[s], end = offsets[s + 1];
        float a0 = 0.f, a1 = 0.f, a2 = 0.f, a3 = 0.f;
        for (int p = beg; p < end; ++p) {
            int srcn = perm[p];
            ushort4 vv = *(const ushort4*)(xb + (long)srcn * ND + fl * 4);
            a0 += bf16_to_f(vv.x); a1 += bf16_to_f(vv.y);
            a2 += bf16_to_f(vv.z); a3 += bf16_to_f(vv.w);
        }
        ushort4 o;
        o.x = bf16_rne(a0); o.y = bf16_rne(a1);
        o.z = bf16_rne(a2); o.w = bf16_rne(a3);
        *(ushort4*)(agbf + (long)node * 512 + r * ND + fl * 4) = o;
    }
}

// ---------------------------------------------------------------- fused node kernel: einsum + residual + MLP1 + relu + MLP2
// Each wave owns 32 nodes end-to-end. msgs/t never leave the CU: the
// C-layout -> A-layout fragment transpose goes through a per-wave LDS tile
// (32 x LPAD f32; bank = (2*row+col)%32 -> conflict-free). All LDS traffic is
// intra-wave (in-order LDS pipe) -> no __syncthreads; explicit lgkmcnt fence.
__global__ __launch_bounds__(256) void fused_node_kernel(
    const unsigned short* __restrict__ agbf, const unsigned short* __restrict__ wt,
    const float* __restrict__ xin, const float* __restrict__ eps,
    const unsigned short* __restrict__ wm1t, const float* __restrict__ mb1,
    const unsigned short* __restrict__ wm2t, const float* __restrict__ mb2,
    const float* __restrict__ bias,
    float* __restrict__ out, unsigned short* __restrict__ out_bf, int nNodes)
{
    __shared__ float lt_all[4][32 * LPAD];
    int wv = threadIdx.x >> 6;
    int lane = threadIdx.x & 63;
    int wid = blockIdx.x * 4 + wv;
    int nbase = wid * 32;
    if (nbase >= nNodes) return;
    float* lt = lt_all[wv];

    int r16 = lane & 15;
    int kg  = lane >> 4;
    float epsv = 1.0f + eps[0];

    int n0 = nbase + r16;      if (n0 >= nNodes) n0 = nNodes - 1;
    int n1 = nbase + 16 + r16; if (n1 >= nNodes) n1 = nNodes - 1;

    // ---- phase 1: msgs = ag @ Wt^T (K=512)
    f32x4 acc[2][4];
#pragma unroll
    for (int m = 0; m < 2; ++m)
#pragma unroll
        for (int j = 0; j < 4; ++j) acc[m][j] = (f32x4){0.f, 0.f, 0.f, 0.f};
    {
        const unsigned short* a0p = agbf + (long)n0 * 512 + kg * 8;
        const unsigned short* a1p = agbf + (long)n1 * 512 + kg * 8;
        const unsigned short* bp  = wt + (long)r16 * 512 + kg * 8;
#pragma unroll 4
        for (int kk = 0; kk < 16; ++kk) {
            bf16x8 a0 = *(const bf16x8*)(a0p + kk * 32);
            bf16x8 a1 = *(const bf16x8*)(a1p + kk * 32);
#pragma unroll
            for (int j = 0; j < 4; ++j) {
                bf16x8 b = *(const bf16x8*)(bp + (long)j * 16 * 512 + kk * 32);
                acc[0][j] = __builtin_amdgcn_mfma_f32_16x16x32_bf16(a0, b, acc[0][j], 0, 0, 0);
                acc[1][j] = __builtin_amdgcn_mfma_f32_16x16x32_bf16(a1, b, acc[1][j], 0, 0, 0);
            }
        }
    }

    // ---- transpose msgs: C-layout regs -> LDS (row = m*16+kg*4+reg, col = j*16+r16)
#pragma unroll
    for (int m = 0; m < 2; ++m)
#pragma unroll
        for (int reg = 0; reg < 4; ++reg) {
            int row = m * 16 + kg * 4 + reg;
#pragma unroll
            for (int j = 0; j < 4; ++j)
                lt[row * LPAD + j * 16 + r16] = acc[m][j][reg];
        }
    asm volatile("s_waitcnt lgkmcnt(0)" ::: "memory");

    // ---- phase 2: h = (1+eps)*x + msgs; t = relu(h @ wm1t^T + mb1)  (K=64)
    f32x4 acc2[2][4];
#pragma unroll
    for (int m = 0; m < 2; ++m)
#pragma unroll
        for (int j = 0; j < 4; ++j) acc2[m][j] = (f32x4){0.f, 0.f, 0.f, 0.f};
#pragma unroll
    for (int m = 0; m < 2; ++m) {
        int rowl = m * 16 + r16;              // row within wave tile
        long nrow = (m == 0) ? n0 : n1;
#pragma unroll
        for (int kk = 0; kk < 2; ++kk) {
            int k0 = kk * 32 + kg * 8;
            float4 x0 = *(const float4*)(xin + nrow * ND + k0);
            float4 x1 = *(const float4*)(xin + nrow * ND + k0 + 4);
            float4 m0 = *(const float4*)(lt + rowl * LPAD + k0);
            float4 m1 = *(const float4*)(lt + rowl * LPAD + k0 + 4);
            us8 u;
            u[0] = bf16_rne(fmaf(epsv, x0.x, m0.x));
            u[1] = bf16_rne(fmaf(epsv, x0.y, m0.y));
            u[2] = bf16_rne(fmaf(epsv, x0.z, m0.z));
            u[3] = bf16_rne(fmaf(epsv, x0.w, m0.w));
            u[4] = bf16_rne(fmaf(epsv, x1.x, m1.x));
            u[5] = bf16_rne(fmaf(epsv, x1.y, m1.y));
            u[6] = bf16_rne(fmaf(epsv, x1.z, m1.z));
            u[7] = bf16_rne(fmaf(epsv, x1.w, m1.w));
            bf16x8 a = __builtin_bit_cast(bf16x8, u);
#pragma unroll
            for (int j = 0; j < 4; ++j) {
                bf16x8 b = *(const bf16x8*)(wm1t + (long)(j * 16 + r16) * ND + k0);
                acc2[m][j] = __builtin_amdgcn_mfma_f32_16x16x32_bf16(a, b, acc2[m][j], 0, 0, 0);
            }
        }
    }

    // ---- transpose t (with bias+relu): regs -> LDS
    asm volatile("s_waitcnt lgkmcnt(0)" ::: "memory");  // drain phase-2 reads before overwrite
#pragma unroll
    for (int m = 0; m < 2; ++m)
#pragma unroll
        for (int reg = 0; reg < 4; ++reg) {
            int row = m * 16 + kg * 4 + reg;
#pragma unroll
            for (int j = 0; j < 4; ++j) {
                int col = j * 16 + r16;
                lt[row * LPAD + col] = fmaxf(acc2[m][j][reg] + mb1[col], 0.f);
            }
        }
    asm volatile("s_waitcnt lgkmcnt(0)" ::: "memory");

    // ---- phase 3: out = t @ wm2t^T + mb2 + bias  (K=64)
    f32x4 acc3[2][4];
#pragma unroll
    for (int m = 0; m < 2; ++m)
#pragma unroll
        for (int j = 0; j < 4; ++j) acc3[m][j] = (f32x4){0.f, 0.f, 0.f, 0.f};
#pragma unroll
    for (int m = 0; m < 2; ++m) {
        int rowl = m * 16 + r16;
#pragma unroll
        for (int kk = 0; kk < 2; ++kk) {
            int k0 = kk * 32 + kg * 8;
            float4 t0 = *(const float4*)(lt + rowl * LPAD + k0);
            float4 t1 = *(const float4*)(lt + rowl * LPAD + k0 + 4);
            us8 u;
            u[0] = bf16_rne(t0.x); u[1] = bf16_rne(t0.y);
            u[2] = bf16_rne(t0.z); u[3] = bf16_rne(t0.w);
            u[4] = bf16_rne(t1.x); u[5] = bf16_rne(t1.y);
            u[6] = bf16_rne(t1.z); u[7] = bf16_rne(t1.w);
            bf16x8 a = __builtin_bit_cast(bf16x8, u);
#pragma unroll
            for (int j = 0; j < 4; ++j) {
                bf16x8 b = *(const bf16x8*)(wm2t + (long)(j * 16 + r16) * ND + k0);
                acc3[m][j] = __builtin_amdgcn_mfma_f32_16x16x32_bf16(a, b, acc3[m][j], 0, 0, 0);
            }
        }
    }

    // ---- epilogue: out (f32) + optional bf16 copy
#pragma unroll
    for (int m = 0; m < 2; ++m) {
#pragma unroll
        for (int reg = 0; reg < 4; ++reg) {
            int row = nbase + m * 16 + kg * 4 + reg;
            if (row < nNodes) {
#pragma unroll
                for (int j = 0; j < 4; ++j) {
                    int col = j * 16 + r16;
                    float v = acc3[m][j][reg] + mb2[col] + bias[col];
                    out[(long)row * ND + col] = v;
                    if (out_bf != nullptr)
                        out_bf[(long)row * ND + col] = bf16_rne(v);
                }
            }
        }
    }
}

// ---------------------------------------------------------------- launch
extern "C" void kernel_launch(void* const* d_in, const int* in_sizes, int n_in,
                              void* d_out, int out_size, void* d_ws, size_t ws_size,
                              hipStream_t stream) {
    const float* x    = (const float*)d_in[0];
    const int* esrc   = (const int*)d_in[1];
    const int* edst   = (const int*)d_in[2];
    const int* etyp   = (const int*)d_in[3];

    const float* W1   = (const float*)d_in[4];
    const float* b1   = (const float*)d_in[5];
    const float* e1   = (const float*)d_in[6];
    const float* m1w1 = (const float*)d_in[7];
    const float* m1b1 = (const float*)d_in[8];
    const float* m1w2 = (const float*)d_in[9];
    const float* m1b2 = (const float*)d_in[10];

    const float* W2   = (const float*)d_in[11];
    const float* b2   = (const float*)d_in[12];
    const float* e2   = (const float*)d_in[13];
    const float* m2w1 = (const float*)d_in[14];
    const float* m2b1 = (const float*)d_in[15];
    const float* m2w2 = (const float*)d_in[16];
    const float* m2b2 = (const float*)d_in[17];

    int nNodes = in_sizes[0] / ND;   // 50000
    int nEdges = in_sizes[1];        // 1600000
    int ntiles = (nNodes + 31) / 32; // 1563
    int Stot = ntiles * 256;         // 400128 segments (incl. padding nodes)

    // ---- workspace layout (~112 MB)
    unsigned short* agbf = (unsigned short*)d_ws;                 // N*512 bf16 = 51.2MB
    unsigned short* xhbf = agbf + (long)nNodes * 512;             // N*64 bf16 = 6.4MB
    unsigned short* wt1  = xhbf + (long)nNodes * ND;
    unsigned short* wt2  = wt1 + 64 * 512;
    unsigned short* wm11 = wt2 + 64 * 512;
    unsigned short* wm12 = wm11 + 64 * 64;
    unsigned short* wm21 = wm12 + 64 * 64;
    unsigned short* wm22 = wm21 + 64 * 64;
    uint2* bbufA  = (uint2*)(wm22 + 64 * 64);                     // 13.8MB
    uint2* bbufB  = bbufA + (long)NSLICE * CAPA;                  // 19.3MB
    int* cnts     = (int*)(bbufB + (long)NTILE_AL * CAPB);
    int* bcur     = cnts;                                         // 8
    int* tilecur  = cnts + NSLICE;                                // 1568
    int* tilebase = tilecur + NTILE_AL;                           // 1568
    int* offsets  = tilebase + NTILE_AL;                          // Stot+1
    int* perm     = offsets + (Stot + 256);                       // E ints = 6.4MB
    float* h    = (float*)d_out;   // layer-1 fp32 h aliases d_out
    float* outp = (float*)d_out;

    int fgrid = (ntiles + 3) / 4;    // 4 waves/block, 32 nodes/wave
    int n8 = nNodes * ND / 8;
    int cvtotal = 65536 + 16384 + n8;

    // ---- build per-segment CSR via LDS-staged two-level bucketing (all dense writes)
    zeroi_kernel<<<7, 256, 0, stream>>>(cnts, NSLICE + NTILE_AL);
    bucket8_kernel<<<782, 256, 0, stream>>>(esrc, edst, etyp, bcur, bbufA, nEdges);
    subbucket_kernel<<<320, 256, 0, stream>>>(bbufA, bcur, tilecur, bbufB);
    tilescan_kernel<<<1, 256, 0, stream>>>(tilecur, tilebase, offsets, NTILE_AL, ntiles, nEdges);
    tilesort_kernel<<<ntiles, 256, 0, stream>>>(bbufB, tilecur, tilebase, offsets, perm);

    // ---- all weight/x converts in one launch
    convert_all_kernel<<<(cvtotal + 255) / 256, 256, 0, stream>>>(
        W1, W2, m1w1, m1w2, m2w1, m2w2, (const float4*)x,
        wt1, wt2, wm11, wm12, wm21, wm22, xhbf, n8);

    // ---- layer 1
    gather_kernel<<<2048, 256, 0, stream>>>(xhbf, offsets, perm, agbf, Stot, nNodes);
    fused_node_kernel<<<fgrid, 256, 0, stream>>>(agbf, wt1, x, e1, wm11, m1b1,
                                                 wm12, m1b2, b1, h, xhbf, nNodes);

    // ---- layer 2
    gather_kernel<<<2048, 256, 0, stream>>>(xhbf, offsets, perm, agbf, Stot, nNodes);
    fused_node_kernel<<<fgrid, 256, 0, stream>>>(agbf, wt2, h, e2, wm21, m2b1,
                                                 wm22, m2b2, b2, outp, nullptr, nNodes);
}

// Round 14
// 231.334 us; speedup vs baseline: 6.0451x; 1.1266x over previous
//
#include <hip/hip_runtime.h>

#define ND 64        // feature dim
#define NR 8         // num edge types
#define NSLICE 8     // dst slices (XCD count)
#define SLICE_NODES 6272   // 196*32; 8*6272 >= 50000
#define TPS 196      // tiles per slice (32 nodes each)
#define NTILE_AL 1568
#define CAPA 216064  // per-slice bucket capacity (mean 200704, ~35 sigma)
#define CAPB 1536    // per-tile bucket capacity (mean 1024, 16 sigma)
#define LPAD 66      // LDS transpose row stride (bank-conflict-free)

typedef __bf16 bf16x8 __attribute__((ext_vector_type(8)));
typedef float f32x4 __attribute__((ext_vector_type(4)));
typedef unsigned short us8 __attribute__((ext_vector_type(8)));

__device__ inline unsigned short bf16_rne(float f) {
    unsigned u = __float_as_uint(f);
    unsigned r = (u + 0x7FFFu + ((u >> 16) & 1u)) >> 16;
    return (unsigned short)r;
}
__device__ inline float bf16_to_f(unsigned short s) {
    return __uint_as_float(((unsigned)s) << 16);
}

// ---------------------------------------------------------------- zero ints
__global__ __launch_bounds__(256) void zeroi_kernel(int* __restrict__ p, int n) {
    int i = blockIdx.x * 256 + threadIdx.x;
    int stride = gridDim.x * 256;
    for (; i < n; i += stride) p[i] = 0;
}

// ---------------------------------------------------------------- A1: bucket edges into 8 dst-slices (proven R10)
__global__ __launch_bounds__(256) void bucket8_kernel(
    const int* __restrict__ src, const int* __restrict__ dst,
    const int* __restrict__ typ, int* __restrict__ bcur,
    uint2* __restrict__ bbufA, int nEdges)
{
    __shared__ uint2 outst[1024];
    __shared__ int lcnt[NSLICE];
    __shared__ int lbase[NSLICE];
    __shared__ int gbase[NSLICE];
    int tid = threadIdx.x;

    for (int base = blockIdx.x * 1024; base < nEdges; base += gridDim.x * 1024) {
        int bn = min(1024, nEdges - base);
        if (tid < NSLICE) lcnt[tid] = 0;
        __syncthreads();
        uint2 ent[4]; int eb[4], eo[4];
#pragma unroll
        for (int k = 0; k < 4; ++k) {
            int i = tid + k * 256;
            eb[k] = -1;
            if (i < bn) {
                int e = base + i;
                int d = dst[e];
                int s = d / SLICE_NODES;
                eb[k] = s;
                ent[k].x = (unsigned)src[e];
                ent[k].y = ((unsigned)s << 16) | ((unsigned)typ[e] << 13) |
                           (unsigned)(d - s * SLICE_NODES);
                eo[k] = atomicAdd(&lcnt[s], 1);
            }
        }
        __syncthreads();
        if (tid == 0) {
            int run = 0;
#pragma unroll
            for (int i = 0; i < NSLICE; ++i) { lbase[i] = run; run += lcnt[i]; }
        }
        if (tid < NSLICE && lcnt[tid] > 0) gbase[tid] = atomicAdd(&bcur[tid], lcnt[tid]);
        __syncthreads();
#pragma unroll
        for (int k = 0; k < 4; ++k)
            if (eb[k] >= 0) outst[lbase[eb[k]] + eo[k]] = ent[k];
        __syncthreads();
#pragma unroll
        for (int k = 0; k < 4; ++k) {
            int i = tid + k * 256;
            if (i < bn) {
                uint2 e = outst[i];
                int s = e.y >> 16;
                bbufA[(long)s * CAPA + gbase[s] + (i - lbase[s])] = e;
            }
        }
        __syncthreads();
    }
}

// ---------------------------------------------------------------- A2: per-slice re-bin into 196 node-tiles (proven R10)
__global__ __launch_bounds__(256) void subbucket_kernel(
    const uint2* __restrict__ bbufA, const int* __restrict__ bcur,
    int* __restrict__ tilecur, uint2* __restrict__ bbufB)
{
    __shared__ uint2 outst[2048];
    __shared__ int lcnt[TPS];
    __shared__ int lbase[TPS];
    __shared__ int gbase[TPS];
    __shared__ int scanbuf[256];
    int tid = threadIdx.x;
    int slice = blockIdx.x & 7;
    int chunk = blockIdx.x >> 3;
    int nchunk = gridDim.x >> 3;
    int n = bcur[slice];
    const uint2* in = bbufA + (long)slice * CAPA;
    int per = (n + nchunk - 1) / nchunk;
    int beg = chunk * per;
    int end = min(beg + per, n);

    for (int b0 = beg; b0 < end; b0 += 2048) {
        int bn = min(2048, end - b0);
        if (tid < TPS) lcnt[tid] = 0;
        __syncthreads();
        uint2 ent[8]; int eb[8], eo[8];
#pragma unroll
        for (int k = 0; k < 8; ++k) {
            int i = tid + k * 256;
            eb[k] = -1;
            if (i < bn) {
                ent[k] = in[b0 + i];
                int bin = (ent[k].y & 8191u) >> 5;
                eb[k] = bin;
                eo[k] = atomicAdd(&lcnt[bin], 1);
            }
        }
        __syncthreads();
        int v = (tid < TPS) ? lcnt[tid] : 0;
        scanbuf[tid] = v;
        __syncthreads();
        int xs = v;
        for (int off = 1; off < 256; off <<= 1) {
            int y = (tid >= off) ? scanbuf[tid - off] : 0;
            __syncthreads();
            xs += y;
            scanbuf[tid] = xs;
            __syncthreads();
        }
        if (tid < TPS) {
            lbase[tid] = xs - v;
            if (v > 0) gbase[tid] = atomicAdd(&tilecur[slice * TPS + tid], v);
        }
        __syncthreads();
#pragma unroll
        for (int k = 0; k < 8; ++k)
            if (eb[k] >= 0) outst[lbase[eb[k]] + eo[k]] = ent[k];
        __syncthreads();
#pragma unroll
        for (int k = 0; k < 8; ++k) {
            int i = tid + k * 256;
            if (i < bn) {
                uint2 e = outst[i];
                int bin = (e.y & 8191u) >> 5;
                bbufB[(long)(slice * TPS + bin) * CAPB + gbase[bin] + (i - lbase[bin])] = e;
            }
        }
        __syncthreads();
    }
}

// ---------------------------------------------------------------- tilescan: prefix over per-tile counts (1 block)
__global__ __launch_bounds__(256) void tilescan_kernel(
    const int* __restrict__ tilecur, int* __restrict__ tilebase,
    int* __restrict__ offsets, int ntAl, int ntUsed, int nEdges)
{
    __shared__ int lds[256];
    int tid = threadIdx.x;
    int v[7]; int lsum = 0;
#pragma unroll
    for (int k = 0; k < 7; ++k) {
        int i = tid * 7 + k;
        v[k] = (i < ntAl) ? tilecur[i] : 0;
        lsum += v[k];
    }
    lds[tid] = lsum;
    __syncthreads();
    int x = lsum;
    for (int off = 1; off < 256; off <<= 1) {
        int y = (tid >= off) ? lds[tid - off] : 0;
        __syncthreads();
        x += y;
        lds[tid] = x;
        __syncthreads();
    }
    int run = x - lsum;
#pragma unroll
    for (int k = 0; k < 7; ++k) {
        int i = tid * 7 + k;
        if (i < ntAl) tilebase[i] = run;
        run += v[k];
    }
    if (tid == 0) offsets[(long)ntUsed * 256] = nEdges;  // sentinel end
}

// ---------------------------------------------------------------- tilesort: per-tile LDS counting sort -> CSR
__global__ __launch_bounds__(256) void tilesort_kernel(
    const uint2* __restrict__ bbufB, const int* __restrict__ tilecur,
    const int* __restrict__ tilebase, int* __restrict__ offsets,
    int* __restrict__ perm)
{
    __shared__ int outst[CAPB];
    __shared__ int lcnt[256];
    __shared__ int sbuf[256];
    __shared__ int cur[256];
    int t = blockIdx.x;
    int tid = threadIdx.x;
    int n = tilecur[t];
    int base = tilebase[t];
    const uint2* buf = bbufB + (long)t * CAPB;

    lcnt[tid] = 0;
    __syncthreads();
    for (int i = tid; i < n; i += 256) {
        uint2 e = buf[i];
        int k = (((e.y >> 13) & 7) << 5) | (e.y & 31);   // r*32 + nl
        atomicAdd(&lcnt[k], 1);
    }
    __syncthreads();
    int v = lcnt[tid];
    sbuf[tid] = v;
    __syncthreads();
    int x = v;
    for (int off = 1; off < 256; off <<= 1) {
        int y = (tid >= off) ? sbuf[tid - off] : 0;
        __syncthreads();
        x += y;
        sbuf[tid] = x;
        __syncthreads();
    }
    int pfx = x - v;
    cur[tid] = pfx;
    offsets[(long)t * 256 + tid] = base + pfx;
    __syncthreads();
    for (int i = tid; i < n; i += 256) {
        uint2 e = buf[i];
        int k = (((e.y >> 13) & 7) << 5) | (e.y & 31);
        int pos = atomicAdd(&cur[k], 1);
        outst[pos] = (int)e.x;
    }
    __syncthreads();
    for (int i = tid; i < n; i += 256) perm[base + i] = outst[i];
}

// ---------------------------------------------------------------- convert_all: wt1|wt2|wm11|wm12|wm21|wm22|xhbf in one launch
__global__ __launch_bounds__(256) void convert_all_kernel(
    const float* __restrict__ W1, const float* __restrict__ W2,
    const float* __restrict__ m1w1, const float* __restrict__ m1w2,
    const float* __restrict__ m2w1, const float* __restrict__ m2w2,
    const float4* __restrict__ x,
    unsigned short* __restrict__ wt1, unsigned short* __restrict__ wt2,
    unsigned short* __restrict__ wm11, unsigned short* __restrict__ wm12,
    unsigned short* __restrict__ wm21, unsigned short* __restrict__ wm22,
    unsigned short* __restrict__ xb, int n8)
{
    int idx = blockIdx.x * 256 + threadIdx.x;
    if (idx < 65536) {                      // wt: [64 o][512 k] = W[k][o]
        const float* W = (idx < 32768) ? W1 : W2;
        unsigned short* wt = (idx < 32768) ? wt1 : wt2;
        int i = idx & 32767;
        int o = i >> 9, k = i & 511;
        wt[i] = bf16_rne(W[(long)k * 64 + o]);
        return;
    }
    idx -= 65536;
    if (idx < 16384) {                      // wm: [64 o][64 k] = m[k][o]
        int which = idx >> 12;
        const float* m = (which == 0) ? m1w1 : (which == 1) ? m1w2
                       : (which == 2) ? m2w1 : m2w2;
        unsigned short* wm = (which == 0) ? wm11 : (which == 1) ? wm12
                           : (which == 2) ? wm21 : wm22;
        int i = idx & 4095;
        int o = i >> 6, k = i & 63;
        wm[i] = bf16_rne(m[k * 64 + o]);
        return;
    }
    idx -= 16384;
    if (idx < n8) {                         // x -> bf16 (8 elems/thread)
        float4 v0 = x[idx * 2], v1 = x[idx * 2 + 1];
        us8 o;
        o[0] = bf16_rne(v0.x); o[1] = bf16_rne(v0.y);
        o[2] = bf16_rne(v0.z); o[3] = bf16_rne(v0.w);
        o[4] = bf16_rne(v1.x); o[5] = bf16_rne(v1.y);
        o[6] = bf16_rne(v1.z); o[7] = bf16_rne(v1.w);
        *(us8*)(xb + (long)idx * 8) = o;
    }
}

// ---------------------------------------------------------------- gather (4-way segment interleave for MLP)
// Each 16-lane group takes 4 CONSECUTIVE segments (same tile, same r, 4
// consecutive nodes). Per iteration: 4 independent perm loads + 4 independent
// row loads in flight (branchless, clamped index, fma-masked accumulate).
// Iterations per quad = max(len) ~= 7 vs 16 serial -> ~2.3x less exposed latency.
__global__ __launch_bounds__(256) void gather_kernel(
    const unsigned short* __restrict__ xb, const int* __restrict__ offsets,
    const int* __restrict__ perm, unsigned short* __restrict__ agbf,
    int Stot, int nNodes)
{
    int tid = threadIdx.x;
    int gidx = (blockIdx.x * 256 + tid) >> 4;
    int nGroups = (gridDim.x * 256) >> 4;
    int fl = tid & 15;

    for (int s0 = gidx * 4; s0 < Stot; s0 += nGroups * 4) {
        int e0 = offsets[s0];
        int e1 = offsets[s0 + 1];
        int e2 = offsets[s0 + 2];
        int e3 = offsets[s0 + 3];
        int e4 = offsets[s0 + 4];

        float a00 = 0.f, a01 = 0.f, a02 = 0.f, a03 = 0.f;
        float a10 = 0.f, a11 = 0.f, a12 = 0.f, a13 = 0.f;
        float a20 = 0.f, a21 = 0.f, a22 = 0.f, a23 = 0.f;
        float a30 = 0.f, a31 = 0.f, a32 = 0.f, a33 = 0.f;
        int p0 = e0, p1 = e1, p2 = e2, p3 = e3;

        while ((p0 < e1) | (p1 < e2) | (p2 < e3) | (p3 < e4)) {
            int q0 = max(min(p0, e1 - 1), 0);
            int q1 = max(min(p1, e2 - 1), 0);
            int q2 = max(min(p2, e3 - 1), 0);
            int q3 = max(min(p3, e4 - 1), 0);
            int i0 = perm[q0];
            int i1 = perm[q1];
            int i2 = perm[q2];
            int i3 = perm[q3];
            ushort4 v0 = *(const ushort4*)(xb + (long)i0 * ND + fl * 4);
            ushort4 v1 = *(const ushort4*)(xb + (long)i1 * ND + fl * 4);
            ushort4 v2 = *(const ushort4*)(xb + (long)i2 * ND + fl * 4);
            ushort4 v3 = *(const ushort4*)(xb + (long)i3 * ND + fl * 4);
            float m0 = (p0 < e1) ? 1.f : 0.f;
            float m1 = (p1 < e2) ? 1.f : 0.f;
            float m2 = (p2 < e3) ? 1.f : 0.f;
            float m3 = (p3 < e4) ? 1.f : 0.f;
            a00 = fmaf(m0, bf16_to_f(v0.x), a00);
            a01 = fmaf(m0, bf16_to_f(v0.y), a01);
            a02 = fmaf(m0, bf16_to_f(v0.z), a02);
            a03 = fmaf(m0, bf16_to_f(v0.w), a03);
            a10 = fmaf(m1, bf16_to_f(v1.x), a10);
            a11 = fmaf(m1, bf16_to_f(v1.y), a11);
            a12 = fmaf(m1, bf16_to_f(v1.z), a12);
            a13 = fmaf(m1, bf16_to_f(v1.w), a13);
            a20 = fmaf(m2, bf16_to_f(v2.x), a20);
            a21 = fmaf(m2, bf16_to_f(v2.y), a21);
            a22 = fmaf(m2, bf16_to_f(v2.z), a22);
            a23 = fmaf(m2, bf16_to_f(v2.w), a23);
            a30 = fmaf(m3, bf16_to_f(v3.x), a30);
            a31 = fmaf(m3, bf16_to_f(v3.y), a31);
            a32 = fmaf(m3, bf16_to_f(v3.z), a32);
            a33 = fmaf(m3, bf16_to_f(v3.w), a33);
            p0 += (p0 < e1); p1 += (p1 < e2); p2 += (p2 < e3); p3 += (p3 < e4);
        }

        // write 4 rows: same tile, same r, consecutive nodes
        int t = s0 >> 8, k0 = s0 & 255;
        int r = k0 >> 5, nl = k0 & 31;
        int node0 = (t << 5) | nl;
        long obase = (long)node0 * 512 + r * ND + fl * 4;
        if (node0 < nNodes) {
            ushort4 o; o.x = bf16_rne(a00); o.y = bf16_rne(a01);
            o.z = bf16_rne(a02); o.w = bf16_rne(a03);
            *(ushort4*)(agbf + obase) = o;
        }
        if (node0 + 1 < nNodes) {
            ushort4 o; o.x = bf16_rne(a10); o.y = bf16_rne(a11);
            o.z = bf16_rne(a12); o.w = bf16_rne(a13);
            *(ushort4*)(agbf + obase + 512) = o;
        }
        if (node0 + 2 < nNodes) {
            ushort4 o; o.x = bf16_rne(a20); o.y = bf16_rne(a21);
            o.z = bf16_rne(a22); o.w = bf16_rne(a23);
            *(ushort4*)(agbf + obase + 1024) = o;
        }
        if (node0 + 3 < nNodes) {
            ushort4 o; o.x = bf16_rne(a30); o.y = bf16_rne(a31);
            o.z = bf16_rne(a32); o.w = bf16_rne(a33);
            *(ushort4*)(agbf + obase + 1536) = o;
        }
    }
}

// ---------------------------------------------------------------- fused node kernel: einsum + residual + MLP1 + relu + MLP2
__global__ __launch_bounds__(256) void fused_node_kernel(
    const unsigned short* __restrict__ agbf, const unsigned short* __restrict__ wt,
    const float* __restrict__ xin, const float* __restrict__ eps,
    const unsigned short* __restrict__ wm1t, const float* __restrict__ mb1,
    const unsigned short* __restrict__ wm2t, const float* __restrict__ mb2,
    const float* __restrict__ bias,
    float* __restrict__ out, unsigned short* __restrict__ out_bf, int nNodes)
{
    __shared__ float lt_all[4][32 * LPAD];
    int wv = threadIdx.x >> 6;
    int lane = threadIdx.x & 63;
    int wid = blockIdx.x * 4 + wv;
    int nbase = wid * 32;
    if (nbase >= nNodes) return;
    float* lt = lt_all[wv];

    int r16 = lane & 15;
    int kg  = lane >> 4;
    float epsv = 1.0f + eps[0];

    int n0 = nbase + r16;      if (n0 >= nNodes) n0 = nNodes - 1;
    int n1 = nbase + 16 + r16; if (n1 >= nNodes) n1 = nNodes - 1;

    // ---- phase 1: msgs = ag @ Wt^T (K=512)
    f32x4 acc[2][4];
#pragma unroll
    for (int m = 0; m < 2; ++m)
#pragma unroll
        for (int j = 0; j < 4; ++j) acc[m][j] = (f32x4){0.f, 0.f, 0.f, 0.f};
    {
        const unsigned short* a0p = agbf + (long)n0 * 512 + kg * 8;
        const unsigned short* a1p = agbf + (long)n1 * 512 + kg * 8;
        const unsigned short* bp  = wt + (long)r16 * 512 + kg * 8;
#pragma unroll 4
        for (int kk = 0; kk < 16; ++kk) {
            bf16x8 a0 = *(const bf16x8*)(a0p + kk * 32);
            bf16x8 a1 = *(const bf16x8*)(a1p + kk * 32);
#pragma unroll
            for (int j = 0; j < 4; ++j) {
                bf16x8 b = *(const bf16x8*)(bp + (long)j * 16 * 512 + kk * 32);
                acc[0][j] = __builtin_amdgcn_mfma_f32_16x16x32_bf16(a0, b, acc[0][j], 0, 0, 0);
                acc[1][j] = __builtin_amdgcn_mfma_f32_16x16x32_bf16(a1, b, acc[1][j], 0, 0, 0);
            }
        }
    }

    // ---- transpose msgs: C-layout regs -> LDS (row = m*16+kg*4+reg, col = j*16+r16)
#pragma unroll
    for (int m = 0; m < 2; ++m)
#pragma unroll
        for (int reg = 0; reg < 4; ++reg) {
            int row = m * 16 + kg * 4 + reg;
#pragma unroll
            for (int j = 0; j < 4; ++j)
                lt[row * LPAD + j * 16 + r16] = acc[m][j][reg];
        }
    asm volatile("s_waitcnt lgkmcnt(0)" ::: "memory");

    // ---- phase 2: h = (1+eps)*x + msgs; t = relu(h @ wm1t^T + mb1)  (K=64)
    f32x4 acc2[2][4];
#pragma unroll
    for (int m = 0; m < 2; ++m)
#pragma unroll
        for (int j = 0; j < 4; ++j) acc2[m][j] = (f32x4){0.f, 0.f, 0.f, 0.f};
#pragma unroll
    for (int m = 0; m < 2; ++m) {
        int rowl = m * 16 + r16;              // row within wave tile
        long nrow = (m == 0) ? n0 : n1;
#pragma unroll
        for (int kk = 0; kk < 2; ++kk) {
            int k0 = kk * 32 + kg * 8;
            float4 x0 = *(const float4*)(xin + nrow * ND + k0);
            float4 x1 = *(const float4*)(xin + nrow * ND + k0 + 4);
            float4 m0 = *(const float4*)(lt + rowl * LPAD + k0);
            float4 m1 = *(const float4*)(lt + rowl * LPAD + k0 + 4);
            us8 u;
            u[0] = bf16_rne(fmaf(epsv, x0.x, m0.x));
            u[1] = bf16_rne(fmaf(epsv, x0.y, m0.y));
            u[2] = bf16_rne(fmaf(epsv, x0.z, m0.z));
            u[3] = bf16_rne(fmaf(epsv, x0.w, m0.w));
            u[4] = bf16_rne(fmaf(epsv, x1.x, m1.x));
            u[5] = bf16_rne(fmaf(epsv, x1.y, m1.y));
            u[6] = bf16_rne(fmaf(epsv, x1.z, m1.z));
            u[7] = bf16_rne(fmaf(epsv, x1.w, m1.w));
            bf16x8 a = __builtin_bit_cast(bf16x8, u);
#pragma unroll
            for (int j = 0; j < 4; ++j) {
                bf16x8 b = *(const bf16x8*)(wm1t + (long)(j * 16 + r16) * ND + k0);
                acc2[m][j] = __builtin_amdgcn_mfma_f32_16x16x32_bf16(a, b, acc2[m][j], 0, 0, 0);
            }
        }
    }

    // ---- transpose t (with bias+relu): regs -> LDS
    asm volatile("s_waitcnt lgkmcnt(0)" ::: "memory");  // drain phase-2 reads before overwrite
#pragma unroll
    for (int m = 0; m < 2; ++m)
#pragma unroll
        for (int reg = 0; reg < 4; ++reg) {
            int row = m * 16 + kg * 4 + reg;
#pragma unroll
            for (int j = 0; j < 4; ++j) {
                int col = j * 16 + r16;
                lt[row * LPAD + col] = fmaxf(acc2[m][j][reg] + mb1[col], 0.f);
            }
        }
    asm volatile("s_waitcnt lgkmcnt(0)" ::: "memory");

    // ---- phase 3: out = t @ wm2t^T + mb2 + bias  (K=64)
    f32x4 acc3[2][4];
#pragma unroll
    for (int m = 0; m < 2; ++m)
#pragma unroll
        for (int j = 0; j < 4; ++j) acc3[m][j] = (f32x4){0.f, 0.f, 0.f, 0.f};
#pragma unroll
    for (int m = 0; m < 2; ++m) {
        int rowl = m * 16 + r16;
#pragma unroll
        for (int kk = 0; kk < 2; ++kk) {
            int k0 = kk * 32 + kg * 8;
            float4 t0 = *(const float4*)(lt + rowl * LPAD + k0);
            float4 t1 = *(const float4*)(lt + rowl * LPAD + k0 + 4);
            us8 u;
            u[0] = bf16_rne(t0.x); u[1] = bf16_rne(t0.y);
            u[2] = bf16_rne(t0.z); u[3] = bf16_rne(t0.w);
            u[4] = bf16_rne(t1.x); u[5] = bf16_rne(t1.y);
            u[6] = bf16_rne(t1.z); u[7] = bf16_rne(t1.w);
            bf16x8 a = __builtin_bit_cast(bf16x8, u);
#pragma unroll
            for (int j = 0; j < 4; ++j) {
                bf16x8 b = *(const bf16x8*)(wm2t + (long)(j * 16 + r16) * ND + k0);
                acc3[m][j] = __builtin_amdgcn_mfma_f32_16x16x32_bf16(a, b, acc3[m][j], 0, 0, 0);
            }
        }
    }

    // ---- epilogue: out (f32) + optional bf16 copy
#pragma unroll
    for (int m = 0; m < 2; ++m) {
#pragma unroll
        for (int reg = 0; reg < 4; ++reg) {
            int row = nbase + m * 16 + kg * 4 + reg;
            if (row < nNodes) {
#pragma unroll
                for (int j = 0; j < 4; ++j) {
                    int col = j * 16 + r16;
                    float v = acc3[m][j][reg] + mb2[col] + bias[col];
                    out[(long)row * ND + col] = v;
                    if (out_bf != nullptr)
                        out_bf[(long)row * ND + col] = bf16_rne(v);
                }
            }
        }
    }
}

// ---------------------------------------------------------------- launch
extern "C" void kernel_launch(void* const* d_in, const int* in_sizes, int n_in,
                              void* d_out, int out_size, void* d_ws, size_t ws_size,
                              hipStream_t stream) {
    const float* x    = (const float*)d_in[0];
    const int* esrc   = (const int*)d_in[1];
    const int* edst   = (const int*)d_in[2];
    const int* etyp   = (const int*)d_in[3];

    const float* W1   = (const float*)d_in[4];
    const float* b1   = (const float*)d_in[5];
    const float* e1   = (const float*)d_in[6];
    const float* m1w1 = (const float*)d_in[7];
    const float* m1b1 = (const float*)d_in[8];
    const float* m1w2 = (const float*)d_in[9];
    const float* m1b2 = (const float*)d_in[10];

    const float* W2   = (const float*)d_in[11];
    const float* b2   = (const float*)d_in[12];
    const float* e2   = (const float*)d_in[13];
    const float* m2w1 = (const float*)d_in[14];
    const float* m2b1 = (const float*)d_in[15];
    const float* m2w2 = (const float*)d_in[16];
    const float* m2b2 = (const float*)d_in[17];

    int nNodes = in_sizes[0] / ND;   // 50000
    int nEdges = in_sizes[1];        // 1600000
    int ntiles = (nNodes + 31) / 32; // 1563
    int Stot = ntiles * 256;         // 400128 segments (incl. padding nodes)

    // ---- workspace layout (~112 MB)
    unsigned short* agbf = (unsigned short*)d_ws;                 // N*512 bf16 = 51.2MB
    unsigned short* xhbf = agbf + (long)nNodes * 512;             // N*64 bf16 = 6.4MB
    unsigned short* wt1  = xhbf + (long)nNodes * ND;
    unsigned short* wt2  = wt1 + 64 * 512;
    unsigned short* wm11 = wt2 + 64 * 512;
    unsigned short* wm12 = wm11 + 64 * 64;
    unsigned short* wm21 = wm12 + 64 * 64;
    unsigned short* wm22 = wm21 + 64 * 64;
    uint2* bbufA  = (uint2*)(wm22 + 64 * 64);                     // 13.8MB
    uint2* bbufB  = bbufA + (long)NSLICE * CAPA;                  // 19.3MB
    int* cnts     = (int*)(bbufB + (long)NTILE_AL * CAPB);
    int* bcur     = cnts;                                         // 8
    int* tilecur  = cnts + NSLICE;                                // 1568
    int* tilebase = tilecur + NTILE_AL;                           // 1568
    int* offsets  = tilebase + NTILE_AL;                          // Stot+1
    int* perm     = offsets + (Stot + 256);                       // E ints = 6.4MB
    float* h    = (float*)d_out;   // layer-1 fp32 h aliases d_out
    float* outp = (float*)d_out;

    int fgrid = (ntiles + 3) / 4;    // 4 waves/block, 32 nodes/wave
    int n8 = nNodes * ND / 8;
    int cvtotal = 65536 + 16384 + n8;

    // ---- build per-segment CSR via LDS-staged two-level bucketing (all dense writes)
    zeroi_kernel<<<7, 256, 0, stream>>>(cnts, NSLICE + NTILE_AL);
    bucket8_kernel<<<782, 256, 0, stream>>>(esrc, edst, etyp, bcur, bbufA, nEdges);
    subbucket_kernel<<<320, 256, 0, stream>>>(bbufA, bcur, tilecur, bbufB);
    tilescan_kernel<<<1, 256, 0, stream>>>(tilecur, tilebase, offsets, NTILE_AL, ntiles, nEdges);
    tilesort_kernel<<<ntiles, 256, 0, stream>>>(bbufB, tilecur, tilebase, offsets, perm);

    // ---- all weight/x converts in one launch
    convert_all_kernel<<<(cvtotal + 255) / 256, 256, 0, stream>>>(
        W1, W2, m1w1, m1w2, m2w1, m2w2, (const float4*)x,
        wt1, wt2, wm11, wm12, wm21, wm22, xhbf, n8);

    // ---- layer 1
    gather_kernel<<<2048, 256, 0, stream>>>(xhbf, offsets, perm, agbf, Stot, nNodes);
    fused_node_kernel<<<fgrid, 256, 0, stream>>>(agbf, wt1, x, e1, wm11, m1b1,
                                                 wm12, m1b2, b1, h, xhbf, nNodes);

    // ---- layer 2
    gather_kernel<<<2048, 256, 0, stream>>>(xhbf, offsets, perm, agbf, Stot, nNodes);
    fused_node_kernel<<<fgrid, 256, 0, stream>>>(agbf, wt2, h, e2, wm21, m2b1,
                                                 wm22, m2b2, b2, outp, nullptr, nNodes);
}